// Round 1
// baseline (9794.007 us; speedup 1.0000x reference)
//
#include <hip/hip_runtime.h>
#include <math.h>

namespace {

constexpr int B = 4, N = 1024, D = 512, H = 8, DHd = 64, L = 6, DFFd = 2048;
constexpr float NEG = -1000000000.0f;
constexpr float R2c = 100.0f;

// ---------------- bias: (B,N,N) additive mask ----------------
__global__ __launch_bounds__(256) void bias_kernel(
    const float* __restrict__ xy, const int* __restrict__ alive,
    const int* __restrict__ species, float* __restrict__ bias)
{
  int j = blockIdx.x * 256 + threadIdx.x;
  int i = blockIdx.y;
  int b = blockIdx.z;
  float xi = xy[((size_t)b * N + i) * 2 + 0];
  float yi = xy[((size_t)b * N + i) * 2 + 1];
  float xj = xy[((size_t)b * N + j) * 2 + 0];
  float yj = xy[((size_t)b * N + j) * 2 + 1];
  float dx = xi - xj, dy = yi - yj;
  float d2 = dx * dx + dy * dy;
  float bv = 0.0f;
  if (alive[b * N + j] == 0) bv += NEG;
  if (d2 > R2c) bv += NEG;
  int si = species[b * N + i], sj = species[b * N + j];
  bool ia = si < 2, ip = si == 2, ja = sj < 2, jp = sj == 2;
  if ((ia && jp) || (ip && ja)) bv += NEG;
  bias[((size_t)b * N + i) * N + j] = bv;
}

// ---------------- LayerNorm: one wave per row of 512 ----------------
__global__ __launch_bounds__(64) void ln_kernel(
    const float* __restrict__ x, const float* __restrict__ g,
    const float* __restrict__ be, float* __restrict__ out)
{
  int row = blockIdx.x;
  int tid = threadIdx.x;
  const float* xr = x + (size_t)row * D;
  float v[8];
  float sum = 0.f;
#pragma unroll
  for (int i = 0; i < 8; ++i) { v[i] = xr[tid + i * 64]; sum += v[i]; }
#pragma unroll
  for (int off = 32; off > 0; off >>= 1) sum += __shfl_down(sum, off);
  sum = __shfl(sum, 0);
  float mean = sum * (1.0f / D);
  float vs = 0.f;
#pragma unroll
  for (int i = 0; i < 8; ++i) { float d = v[i] - mean; vs += d * d; }
#pragma unroll
  for (int off = 32; off > 0; off >>= 1) vs += __shfl_down(vs, off);
  vs = __shfl(vs, 0);
  float rstd = rsqrtf(vs * (1.0f / D) + 1e-5f);
  float* orow = out + (size_t)row * D;
#pragma unroll
  for (int i = 0; i < 8; ++i) {
    int c = tid + i * 64;
    orow[c] = (v[i] - mean) * rstd * g[c] + be[c];
  }
}

__device__ __forceinline__ float gelu_f(float x) {
  return 0.5f * x * (1.0f + erff(x * 0.70710678118654752f));
}

// ---------------- fp32 tiled GEMM: C = act(A@W + bvec + resid) ----------------
// A: MxK row-major, W: KxNc row-major, C: MxNc. 64x64 tile, BK=16, 256 thr, 4x4/thr.
__global__ __launch_bounds__(256) void gemm_kernel(
    const float* __restrict__ A, const float* __restrict__ W,
    const float* __restrict__ bvec, const float* __restrict__ resid,
    float* __restrict__ C, int M, int K, int Nc, int act)
{
  __shared__ float As[16][64];
  __shared__ float Ws[16][64];
  int bm = blockIdx.y * 64;
  int bn = blockIdx.x * 64;
  int tid = threadIdx.x;
  int tx = tid & 15, ty = tid >> 4;
  float acc[4][4] = {};
  int lm = tid >> 2, lkq = (tid & 3) * 4;   // A-tile load coords
  int lk = tid >> 4, lnq = (tid & 15) * 4;  // W-tile load coords
  for (int k0 = 0; k0 < K; k0 += 16) {
    float4 av = *(const float4*)&A[(size_t)(bm + lm) * K + k0 + lkq];
    As[lkq + 0][lm] = av.x;
    As[lkq + 1][lm] = av.y;
    As[lkq + 2][lm] = av.z;
    As[lkq + 3][lm] = av.w;
    float4 wv = *(const float4*)&W[(size_t)(k0 + lk) * Nc + bn + lnq];
    *(float4*)&Ws[lk][lnq] = wv;
    __syncthreads();
#pragma unroll
    for (int kk = 0; kk < 16; ++kk) {
      float a[4], w[4];
#pragma unroll
      for (int i = 0; i < 4; ++i) a[i] = As[kk][ty * 4 + i];
#pragma unroll
      for (int j = 0; j < 4; ++j) w[j] = Ws[kk][tx * 4 + j];
#pragma unroll
      for (int i = 0; i < 4; ++i)
#pragma unroll
        for (int j = 0; j < 4; ++j) acc[i][j] += a[i] * w[j];
    }
    __syncthreads();
  }
#pragma unroll
  for (int i = 0; i < 4; ++i) {
    int row = bm + ty * 4 + i;
    int col = bn + tx * 4;
    float4 r;
    float o0 = acc[i][0], o1 = acc[i][1], o2 = acc[i][2], o3 = acc[i][3];
    if (bvec) {
      o0 += bvec[col + 0]; o1 += bvec[col + 1];
      o2 += bvec[col + 2]; o3 += bvec[col + 3];
    }
    if (resid) {
      float4 rv = *(const float4*)&resid[(size_t)row * Nc + col];
      o0 += rv.x; o1 += rv.y; o2 += rv.z; o3 += rv.w;
    }
    if (act == 1) {
      o0 = gelu_f(o0); o1 = gelu_f(o1); o2 = gelu_f(o2); o3 = gelu_f(o3);
    }
    r.x = o0; r.y = o1; r.z = o2; r.w = o3;
    *(float4*)&C[(size_t)row * Nc + col] = r;
  }
}

// ---------------- attention: one wave per (b, h, query i) ----------------
// q,k,v layout (B,N,H,DH) contiguous == (B,N,D) with col = h*64+d.
__global__ __launch_bounds__(64) void attn_kernel(
    const float* __restrict__ q, const float* __restrict__ k,
    const float* __restrict__ v, const float* __restrict__ bias,
    float* __restrict__ o)
{
  int i = blockIdx.x, hh = blockIdx.y, b = blockIdx.z;
  int tid = threadIdx.x;
  __shared__ float s[N];
  __shared__ float qv[DHd];
  qv[tid] = q[(((size_t)b * N + i) * H + hh) * DHd + tid];
  __syncthreads();
  const float* kb = k + (size_t)b * N * D + hh * DHd;
  const float* brow = bias + ((size_t)b * N + i) * N;
  for (int j = tid; j < N; j += 64) {
    const float4* kp = (const float4*)(kb + (size_t)j * D);
    float dot = 0.f;
#pragma unroll
    for (int d4 = 0; d4 < 16; ++d4) {
      float4 kv = kp[d4];
      dot += qv[d4 * 4 + 0] * kv.x + qv[d4 * 4 + 1] * kv.y +
             qv[d4 * 4 + 2] * kv.z + qv[d4 * 4 + 3] * kv.w;
    }
    s[j] = dot * 0.125f + brow[j];
  }
  __syncthreads();
  float mx = -INFINITY;
  for (int j = tid; j < N; j += 64) mx = fmaxf(mx, s[j]);
#pragma unroll
  for (int off = 32; off > 0; off >>= 1) mx = fmaxf(mx, __shfl_down(mx, off));
  mx = __shfl(mx, 0);
  float sum = 0.f;
  for (int j = tid; j < N; j += 64) {
    float e = __expf(s[j] - mx);
    s[j] = e;
    sum += e;
  }
#pragma unroll
  for (int off = 32; off > 0; off >>= 1) sum += __shfl_down(sum, off);
  sum = __shfl(sum, 0);
  float inv = 1.0f / sum;
  __syncthreads();
  const float* vb = v + (size_t)b * N * D + hh * DHd + tid;
  float acc = 0.f;
  for (int j = 0; j < N; j += 4) {
    acc += s[j + 0] * vb[(size_t)(j + 0) * D];
    acc += s[j + 1] * vb[(size_t)(j + 1) * D];
    acc += s[j + 2] * vb[(size_t)(j + 2) * D];
    acc += s[j + 3] * vb[(size_t)(j + 3) * D];
  }
  o[(((size_t)b * N + i) * H + hh) * DHd + tid] = acc * inv;
}

}  // namespace

extern "C" void kernel_launch(void* const* d_in, const int* in_sizes, int n_in,
                              void* d_out, int out_size, void* d_ws, size_t ws_size,
                              hipStream_t stream)
{
  const float* tokens  = (const float*)d_in[0];
  const float* xy      = (const float*)d_in[1];
  const float* Wq      = (const float*)d_in[2];
  const float* Wk      = (const float*)d_in[3];
  const float* Wv      = (const float*)d_in[4];
  const float* Wo      = (const float*)d_in[5];
  const float* bo      = (const float*)d_in[6];
  const float* W1      = (const float*)d_in[7];
  const float* b1      = (const float*)d_in[8];
  const float* W2      = (const float*)d_in[9];
  const float* b2      = (const float*)d_in[10];
  const float* g1      = (const float*)d_in[11];
  const float* be1     = (const float*)d_in[12];
  const float* g2      = (const float*)d_in[13];
  const float* be2     = (const float*)d_in[14];
  const float* gf      = (const float*)d_in[15];
  const float* bf      = (const float*)d_in[16];
  const int*   alive   = (const int*)d_in[17];
  const int*   species = (const int*)d_in[18];

  float* ws   = (float*)d_ws;
  float* bias = ws;                           // B*N*N   = 4,194,304 f
  float* x    = bias + (size_t)B * N * N;     // B*N*D   = 2,097,152 f
  float* h    = x + (size_t)B * N * D;
  float* q    = h + (size_t)B * N * D;
  float* kk   = q + (size_t)B * N * D;
  float* vv   = kk + (size_t)B * N * D;
  float* ff   = vv + (size_t)B * N * D;       // B*N*DFF = 8,388,608 f

  hipMemcpyAsync(x, tokens, sizeof(float) * (size_t)B * N * D,
                 hipMemcpyDeviceToDevice, stream);
  bias_kernel<<<dim3(N / 256, N, B), 256, 0, stream>>>(xy, alive, species, bias);

  const int M = B * N;
  for (int l = 0; l < L; ++l) {
    ln_kernel<<<M, 64, 0, stream>>>(x, g1 + l * D, be1 + l * D, h);
    gemm_kernel<<<dim3(D / 64, M / 64), 256, 0, stream>>>(
        h, Wq + (size_t)l * D * D, nullptr, nullptr, q, M, D, D, 0);
    gemm_kernel<<<dim3(D / 64, M / 64), 256, 0, stream>>>(
        h, Wk + (size_t)l * D * D, nullptr, nullptr, kk, M, D, D, 0);
    gemm_kernel<<<dim3(D / 64, M / 64), 256, 0, stream>>>(
        h, Wv + (size_t)l * D * D, nullptr, nullptr, vv, M, D, D, 0);
    // attention output reuses h (h already consumed by QKV gemms)
    attn_kernel<<<dim3(N, H, B), 64, 0, stream>>>(q, kk, vv, bias, h);
    gemm_kernel<<<dim3(D / 64, M / 64), 256, 0, stream>>>(
        h, Wo + (size_t)l * D * D, bo + l * D, x, x, M, D, D, 0);
    ln_kernel<<<M, 64, 0, stream>>>(x, g2 + l * D, be2 + l * D, h);
    gemm_kernel<<<dim3(DFFd / 64, M / 64), 256, 0, stream>>>(
        h, W1 + (size_t)l * D * DFFd, b1 + l * DFFd, nullptr, ff, M, D, DFFd, 1);
    gemm_kernel<<<dim3(D / 64, M / 64), 256, 0, stream>>>(
        ff, W2 + (size_t)l * DFFd * D, b2 + l * D, x, x, M, DFFd, D, 0);
  }
  ln_kernel<<<M, 64, 0, stream>>>(x, gf, bf, (float*)d_out);
}

// Round 2
// 3173.718 us; speedup vs baseline: 3.0860x; 3.0860x over previous
//
#include <hip/hip_runtime.h>
#include <math.h>

namespace {

constexpr int B = 4, N = 1024, D = 512, H = 8, DHd = 64, L = 6, DFFd = 2048;
constexpr float NEG = -1000000000.0f;
constexpr float R2c = 100.0f;

typedef __attribute__((ext_vector_type(8))) short bf16x8;
typedef __attribute__((ext_vector_type(4))) float f32x4;

__device__ __forceinline__ short f2bf(float f) {
  union { float f; unsigned u; } c; c.f = f;
  unsigned r = (c.u + 0x7fffu + ((c.u >> 16) & 1u)) >> 16;
  return (short)r;
}

// ---------------- bias: (B,N,N) additive mask ----------------
__global__ __launch_bounds__(256) void bias_kernel(
    const float* __restrict__ xy, const int* __restrict__ alive,
    const int* __restrict__ species, float* __restrict__ bias)
{
  int j = blockIdx.x * 256 + threadIdx.x;
  int i = blockIdx.y;
  int b = blockIdx.z;
  float xi = xy[((size_t)b * N + i) * 2 + 0];
  float yi = xy[((size_t)b * N + i) * 2 + 1];
  float xj = xy[((size_t)b * N + j) * 2 + 0];
  float yj = xy[((size_t)b * N + j) * 2 + 1];
  float dx = xi - xj, dy = yi - yj;
  float d2 = dx * dx + dy * dy;
  float bv = 0.0f;
  if (alive[b * N + j] == 0) bv += NEG;
  if (d2 > R2c) bv += NEG;
  int si = species[b * N + i], sj = species[b * N + j];
  bool ia = si < 2, ip = si == 2, ja = sj < 2, jp = sj == 2;
  if ((ia && jp) || (ip && ja)) bv += NEG;
  bias[((size_t)b * N + i) * N + j] = bv;
}

// ---------------- LayerNorm: one wave per row of 512 ----------------
__global__ __launch_bounds__(64) void ln_kernel(
    const float* __restrict__ x, const float* __restrict__ g,
    const float* __restrict__ be, float* __restrict__ out)
{
  int row = blockIdx.x;
  int tid = threadIdx.x;
  const float* xr = x + (size_t)row * D;
  float v[8];
  float sum = 0.f;
#pragma unroll
  for (int i = 0; i < 8; ++i) { v[i] = xr[tid + i * 64]; sum += v[i]; }
#pragma unroll
  for (int off = 32; off > 0; off >>= 1) sum += __shfl_down(sum, off);
  sum = __shfl(sum, 0);
  float mean = sum * (1.0f / D);
  float vs = 0.f;
#pragma unroll
  for (int i = 0; i < 8; ++i) { float d = v[i] - mean; vs += d * d; }
#pragma unroll
  for (int off = 32; off > 0; off >>= 1) vs += __shfl_down(vs, off);
  vs = __shfl(vs, 0);
  float rstd = rsqrtf(vs * (1.0f / D) + 1e-5f);
  float* orow = out + (size_t)row * D;
#pragma unroll
  for (int i = 0; i < 8; ++i) {
    int c = tid + i * 64;
    orow[c] = (v[i] - mean) * rstd * g[c] + be[c];
  }
}

__device__ __forceinline__ float gelu_f(float x) {
  return 0.5f * x * (1.0f + erff(x * 0.70710678118654752f));
}

// ---------------- fp32 tiled GEMM: C = act(A@W + bvec + resid) ----------------
__global__ __launch_bounds__(256) void gemm_kernel(
    const float* __restrict__ A, const float* __restrict__ W,
    const float* __restrict__ bvec, const float* __restrict__ resid,
    float* __restrict__ C, int M, int K, int Nc, int act)
{
  __shared__ float As[16][64];
  __shared__ float Ws[16][64];
  int bm = blockIdx.y * 64;
  int bn = blockIdx.x * 64;
  int tid = threadIdx.x;
  int tx = tid & 15, ty = tid >> 4;
  float acc[4][4] = {};
  int lm = tid >> 2, lkq = (tid & 3) * 4;
  int lk = tid >> 4, lnq = (tid & 15) * 4;
  for (int k0 = 0; k0 < K; k0 += 16) {
    float4 av = *(const float4*)&A[(size_t)(bm + lm) * K + k0 + lkq];
    As[lkq + 0][lm] = av.x;
    As[lkq + 1][lm] = av.y;
    As[lkq + 2][lm] = av.z;
    As[lkq + 3][lm] = av.w;
    float4 wv = *(const float4*)&W[(size_t)(k0 + lk) * Nc + bn + lnq];
    *(float4*)&Ws[lk][lnq] = wv;
    __syncthreads();
#pragma unroll
    for (int kk = 0; kk < 16; ++kk) {
      float a[4], w[4];
#pragma unroll
      for (int i = 0; i < 4; ++i) a[i] = As[kk][ty * 4 + i];
#pragma unroll
      for (int j = 0; j < 4; ++j) w[j] = Ws[kk][tx * 4 + j];
#pragma unroll
      for (int i = 0; i < 4; ++i)
#pragma unroll
        for (int j = 0; j < 4; ++j) acc[i][j] += a[i] * w[j];
    }
    __syncthreads();
  }
#pragma unroll
  for (int i = 0; i < 4; ++i) {
    int row = bm + ty * 4 + i;
    int col = bn + tx * 4;
    float4 r;
    float o0 = acc[i][0], o1 = acc[i][1], o2 = acc[i][2], o3 = acc[i][3];
    if (bvec) {
      o0 += bvec[col + 0]; o1 += bvec[col + 1];
      o2 += bvec[col + 2]; o3 += bvec[col + 3];
    }
    if (resid) {
      float4 rv = *(const float4*)&resid[(size_t)row * Nc + col];
      o0 += rv.x; o1 += rv.y; o2 += rv.z; o3 += rv.w;
    }
    if (act == 1) {
      o0 = gelu_f(o0); o1 = gelu_f(o1); o2 = gelu_f(o2); o3 = gelu_f(o3);
    }
    r.x = o0; r.y = o1; r.z = o2; r.w = o3;
    *(float4*)&C[(size_t)row * Nc + col] = r;
  }
}

// ---------------- MFMA flash attention ----------------
// Workgroup = (qtile of 64, head, batch), 256 threads = 4 waves.
// Wave w handles the 16-query band [q0 + 16w, q0 + 16w + 16).
// q,k,v layout (B,N,H,DH) == (B,N,512) with col = h*64+d.  Output o: fp32 same layout.
__global__ __launch_bounds__(256) void attn_mfma_kernel(
    const float* __restrict__ q, const float* __restrict__ k,
    const float* __restrict__ v, const float* __restrict__ bias,
    float* __restrict__ o)
{
  constexpr int LDR = 72;  // LDS row stride in bf16 elems (144 B: 2-way-free banks)
  __shared__ __align__(16) short Qs[64 * LDR];       // [qrow][dh]
  __shared__ __align__(16) short Ks[64 * LDR];       // [key][dh]
  __shared__ __align__(16) short Vt[64 * LDR];       // [dh][key]  (transposed)
  __shared__ __align__(16) short Ps[4 * 16 * LDR];   // per-wave [qrow16][key64]

  const int q0 = blockIdx.x * 64;
  const int hh = blockIdx.y;
  const int b  = blockIdx.z;
  const int t  = threadIdx.x;
  const int wave = t >> 6;
  const int lane = t & 63;
  const int quad = lane >> 4;   // 0..3
  const int ln16 = lane & 15;   // 0..15

  // ---- stage Q tile (once) ----
  {
    int srow = t >> 2, g = t & 3;
    const float* qb = q + ((size_t)(b * N + q0 + srow)) * D + hh * 64;
#pragma unroll
    for (int r = 0; r < 4; ++r) {
      int dh = g * 4 + r * 16;
      float4 qv = *(const float4*)(qb + dh);
      short4 qs = { f2bf(qv.x), f2bf(qv.y), f2bf(qv.z), f2bf(qv.w) };
      *(short4*)&Qs[srow * LDR + dh] = qs;
    }
  }

  // ---- per-lane softmax state ----
  float m_run[4], l_run[4];
  f32x4 Oacc[4];  // [dtile], rows = quad*4+r, col = dtile*16+ln16
#pragma unroll
  for (int r = 0; r < 4; ++r) { m_run[r] = -1e30f; l_run[r] = 0.f; }
#pragma unroll
  for (int dt = 0; dt < 4; ++dt) Oacc[dt] = (f32x4){0.f, 0.f, 0.f, 0.f};

  short* Psw = Ps + wave * 16 * LDR;
  const size_t brow0 = (size_t)(b * N + q0 + wave * 16 + quad * 4) * N;

  for (int kt = 0; kt < 16; ++kt) {
    const int k0 = kt * 64;
    __syncthreads();  // prev PV done before restaging (also covers Q staging)
    // ---- stage K tile (row-major) and V tile (transposed) ----
    {
      int srow = t >> 2, g = t & 3;
      const float* kb = k + ((size_t)(b * N + k0 + srow)) * D + hh * 64;
      const float* vb = v + ((size_t)(b * N + k0 + srow)) * D + hh * 64;
#pragma unroll
      for (int r = 0; r < 4; ++r) {
        int dh = g * 4 + r * 16;
        float4 kv = *(const float4*)(kb + dh);
        short4 ks = { f2bf(kv.x), f2bf(kv.y), f2bf(kv.z), f2bf(kv.w) };
        *(short4*)&Ks[srow * LDR + dh] = ks;
        float4 vv4 = *(const float4*)(vb + dh);
        Vt[(dh + 0) * LDR + srow] = f2bf(vv4.x);
        Vt[(dh + 1) * LDR + srow] = f2bf(vv4.y);
        Vt[(dh + 2) * LDR + srow] = f2bf(vv4.z);
        Vt[(dh + 3) * LDR + srow] = f2bf(vv4.w);
      }
    }
    __syncthreads();

    // ---- S = Q K^T for this wave's 16-row band ----
    bf16x8 a0 = *(const bf16x8*)&Qs[(wave * 16 + ln16) * LDR + quad * 8];
    bf16x8 a1 = *(const bf16x8*)&Qs[(wave * 16 + ln16) * LDR + 32 + quad * 8];
    f32x4 sc[4];
#pragma unroll
    for (int tile = 0; tile < 4; ++tile) {
      bf16x8 b0 = *(const bf16x8*)&Ks[(tile * 16 + ln16) * LDR + quad * 8];
      bf16x8 b1 = *(const bf16x8*)&Ks[(tile * 16 + ln16) * LDR + 32 + quad * 8];
      f32x4 z = (f32x4){0.f, 0.f, 0.f, 0.f};
      z = __builtin_amdgcn_mfma_f32_16x16x32_bf16(a0, b0, z, 0, 0, 0);
      z = __builtin_amdgcn_mfma_f32_16x16x32_bf16(a1, b1, z, 0, 0, 0);
      sc[tile] = z;
    }

    // ---- scale + bias ----
    float s[4][4];  // [tile][r]
#pragma unroll
    for (int tile = 0; tile < 4; ++tile) {
      int col = k0 + tile * 16 + ln16;
#pragma unroll
      for (int r = 0; r < 4; ++r)
        s[tile][r] = sc[tile][r] * 0.125f + bias[brow0 + (size_t)r * N + col];
    }

    // ---- online softmax ----
    float p[4][4];
#pragma unroll
    for (int r = 0; r < 4; ++r) {
      float mt = fmaxf(fmaxf(s[0][r], s[1][r]), fmaxf(s[2][r], s[3][r]));
#pragma unroll
      for (int off = 1; off < 16; off <<= 1) mt = fmaxf(mt, __shfl_xor(mt, off));
      float m_new = fmaxf(m_run[r], mt);
      float al = __expf(m_run[r] - m_new);
      m_run[r] = m_new;
      float rs = 0.f;
#pragma unroll
      for (int tile = 0; tile < 4; ++tile) {
        float e = __expf(s[tile][r] - m_new);
        p[tile][r] = e;
        rs += e;
      }
#pragma unroll
      for (int off = 1; off < 16; off <<= 1) rs += __shfl_xor(rs, off);
      l_run[r] = l_run[r] * al + rs;
#pragma unroll
      for (int dt = 0; dt < 4; ++dt) Oacc[dt][r] *= al;
    }

    // ---- P (C-layout) -> LDS -> A-layout ----
#pragma unroll
    for (int tile = 0; tile < 4; ++tile)
#pragma unroll
      for (int r = 0; r < 4; ++r)
        Psw[(quad * 4 + r) * LDR + tile * 16 + ln16] = f2bf(p[tile][r]);
    __syncthreads();  // lgkmcnt drain (Ps is wave-private; barrier is uniform)

    // ---- O += P V ----
    bf16x8 ap0 = *(const bf16x8*)&Psw[ln16 * LDR + quad * 8];
    bf16x8 ap1 = *(const bf16x8*)&Psw[ln16 * LDR + 32 + quad * 8];
#pragma unroll
    for (int dt = 0; dt < 4; ++dt) {
      bf16x8 bv0 = *(const bf16x8*)&Vt[(dt * 16 + ln16) * LDR + quad * 8];
      bf16x8 bv1 = *(const bf16x8*)&Vt[(dt * 16 + ln16) * LDR + 32 + quad * 8];
      Oacc[dt] = __builtin_amdgcn_mfma_f32_16x16x32_bf16(ap0, bv0, Oacc[dt], 0, 0, 0);
      Oacc[dt] = __builtin_amdgcn_mfma_f32_16x16x32_bf16(ap1, bv1, Oacc[dt], 0, 0, 0);
    }
  }

  // ---- epilogue: O / l ----
  float inv[4];
#pragma unroll
  for (int r = 0; r < 4; ++r) inv[r] = 1.0f / l_run[r];
#pragma unroll
  for (int dt = 0; dt < 4; ++dt) {
#pragma unroll
    for (int r = 0; r < 4; ++r) {
      int row = q0 + wave * 16 + quad * 4 + r;
      o[((size_t)(b * N + row)) * D + hh * 64 + dt * 16 + ln16] = Oacc[dt][r] * inv[r];
    }
  }
}

}  // namespace

extern "C" void kernel_launch(void* const* d_in, const int* in_sizes, int n_in,
                              void* d_out, int out_size, void* d_ws, size_t ws_size,
                              hipStream_t stream)
{
  const float* tokens  = (const float*)d_in[0];
  const float* xy      = (const float*)d_in[1];
  const float* Wq      = (const float*)d_in[2];
  const float* Wk      = (const float*)d_in[3];
  const float* Wv      = (const float*)d_in[4];
  const float* Wo      = (const float*)d_in[5];
  const float* bo      = (const float*)d_in[6];
  const float* W1      = (const float*)d_in[7];
  const float* b1      = (const float*)d_in[8];
  const float* W2      = (const float*)d_in[9];
  const float* b2      = (const float*)d_in[10];
  const float* g1      = (const float*)d_in[11];
  const float* be1     = (const float*)d_in[12];
  const float* g2      = (const float*)d_in[13];
  const float* be2     = (const float*)d_in[14];
  const float* gf      = (const float*)d_in[15];
  const float* bf      = (const float*)d_in[16];
  const int*   alive   = (const int*)d_in[17];
  const int*   species = (const int*)d_in[18];

  float* ws   = (float*)d_ws;
  float* bias = ws;                           // B*N*N
  float* x    = bias + (size_t)B * N * N;
  float* h    = x + (size_t)B * N * D;
  float* q    = h + (size_t)B * N * D;
  float* kk   = q + (size_t)B * N * D;
  float* vv   = kk + (size_t)B * N * D;
  float* ff   = vv + (size_t)B * N * D;       // B*N*DFF

  hipMemcpyAsync(x, tokens, sizeof(float) * (size_t)B * N * D,
                 hipMemcpyDeviceToDevice, stream);
  bias_kernel<<<dim3(N / 256, N, B), 256, 0, stream>>>(xy, alive, species, bias);

  const int M = B * N;
  for (int l = 0; l < L; ++l) {
    ln_kernel<<<M, 64, 0, stream>>>(x, g1 + l * D, be1 + l * D, h);
    gemm_kernel<<<dim3(D / 64, M / 64), 256, 0, stream>>>(
        h, Wq + (size_t)l * D * D, nullptr, nullptr, q, M, D, D, 0);
    gemm_kernel<<<dim3(D / 64, M / 64), 256, 0, stream>>>(
        h, Wk + (size_t)l * D * D, nullptr, nullptr, kk, M, D, D, 0);
    gemm_kernel<<<dim3(D / 64, M / 64), 256, 0, stream>>>(
        h, Wv + (size_t)l * D * D, nullptr, nullptr, vv, M, D, D, 0);
    attn_mfma_kernel<<<dim3(N / 64, H, B), 256, 0, stream>>>(q, kk, vv, bias, h);
    gemm_kernel<<<dim3(D / 64, M / 64), 256, 0, stream>>>(
        h, Wo + (size_t)l * D * D, bo + l * D, x, x, M, D, D, 0);
    ln_kernel<<<M, 64, 0, stream>>>(x, g2 + l * D, be2 + l * D, h);
    gemm_kernel<<<dim3(DFFd / 64, M / 64), 256, 0, stream>>>(
        h, W1 + (size_t)l * D * DFFd, b1 + l * DFFd, nullptr, ff, M, D, DFFd, 1);
    gemm_kernel<<<dim3(D / 64, M / 64), 256, 0, stream>>>(
        ff, W2 + (size_t)l * DFFd * D, b2 + l * D, x, x, M, DFFd, D, 0);
  }
  ln_kernel<<<M, 64, 0, stream>>>(x, gf, bf, (float*)d_out);
}

// Round 3
// 1251.403 us; speedup vs baseline: 7.8264x; 2.5361x over previous
//
#include <hip/hip_runtime.h>
#include <math.h>

namespace {

constexpr int B = 4, N = 1024, D = 512, H = 8, DHd = 64, L = 6, DFFd = 2048;
constexpr int M = B * N;           // 4096
constexpr int QKVS = 3 * D;        // 1536, qkv row stride
constexpr float NEG = -1000000000.0f;
constexpr float R2c = 100.0f;

typedef __attribute__((ext_vector_type(8))) short bf16x8;
typedef __attribute__((ext_vector_type(4))) float f32x4;

__device__ __forceinline__ short f2bf(float f) {
  union { float f; unsigned u; } c; c.f = f;
  unsigned r = (c.u + 0x7fffu + ((c.u >> 16) & 1u)) >> 16;
  return (short)r;
}

__device__ __forceinline__ float gelu_f(float x) {
  return 0.5f * x * (1.0f + erff(x * 0.70710678118654752f));
}

// ---------------- bias: (B,N,N) additive mask ----------------
__global__ __launch_bounds__(256) void bias_kernel(
    const float* __restrict__ xy, const int* __restrict__ alive,
    const int* __restrict__ species, float* __restrict__ bias)
{
  int j = blockIdx.x * 256 + threadIdx.x;
  int i = blockIdx.y;
  int b = blockIdx.z;
  float xi = xy[((size_t)b * N + i) * 2 + 0];
  float yi = xy[((size_t)b * N + i) * 2 + 1];
  float xj = xy[((size_t)b * N + j) * 2 + 0];
  float yj = xy[((size_t)b * N + j) * 2 + 1];
  float dx = xi - xj, dy = yi - yj;
  float d2 = dx * dx + dy * dy;
  float bv = 0.0f;
  if (alive[b * N + j] == 0) bv += NEG;
  if (d2 > R2c) bv += NEG;
  int si = species[b * N + i], sj = species[b * N + j];
  bool ia = si < 2, ip = si == 2, ja = sj < 2, jp = sj == 2;
  if ((ia && jp) || (ip && ja)) bv += NEG;
  bias[((size_t)b * N + i) * N + j] = bv;
}

// ---------------- weight prep: fp32 (K x Nc) -> bf16 transposed (Nc x K) ----------------
__global__ __launch_bounds__(256) void wprep_kernel(
    const float* __restrict__ src, short* __restrict__ dst,
    int K, int Nc, size_t srcLS, size_t dstLS)
{
  __shared__ float t[32][33];
  int k0 = blockIdx.x * 32, n0 = blockIdx.y * 32;
  src += (size_t)blockIdx.z * srcLS;
  dst += (size_t)blockIdx.z * dstLS;
  int r = threadIdx.x >> 5, c = threadIdx.x & 31;  // r: 0..7
#pragma unroll
  for (int i = 0; i < 4; ++i)
    t[r + i * 8][c] = src[(size_t)(k0 + r + i * 8) * Nc + n0 + c];
  __syncthreads();
#pragma unroll
  for (int i = 0; i < 4; ++i)
    dst[(size_t)(n0 + r + i * 8) * K + k0 + c] = f2bf(t[c][r + i * 8]);
}

// ---------------- LayerNorm: one wave per row of 512; bf16 or fp32 out ----------------
__global__ __launch_bounds__(64) void ln_kernel(
    const float* __restrict__ x, const float* __restrict__ g,
    const float* __restrict__ be, float* __restrict__ outf,
    short* __restrict__ outb)
{
  int row = blockIdx.x;
  int tid = threadIdx.x;
  const float* xr = x + (size_t)row * D;
  float v[8];
  float sum = 0.f;
#pragma unroll
  for (int i = 0; i < 8; ++i) { v[i] = xr[tid + i * 64]; sum += v[i]; }
#pragma unroll
  for (int off = 32; off > 0; off >>= 1) sum += __shfl_down(sum, off);
  sum = __shfl(sum, 0);
  float mean = sum * (1.0f / D);
  float vs = 0.f;
#pragma unroll
  for (int i = 0; i < 8; ++i) { float d = v[i] - mean; vs += d * d; }
#pragma unroll
  for (int off = 32; off > 0; off >>= 1) vs += __shfl_down(vs, off);
  vs = __shfl(vs, 0);
  float rstd = rsqrtf(vs * (1.0f / D) + 1e-5f);
#pragma unroll
  for (int i = 0; i < 8; ++i) {
    int c = tid + i * 64;
    float o = (v[i] - mean) * rstd * g[c] + be[c];
    if (outb) outb[(size_t)row * D + c] = f2bf(o);
    else      outf[(size_t)row * D + c] = o;
  }
}

// ---------------- bf16 MFMA GEMM (m97 structure) ----------------
// A: MxK bf16 row-major. Bt: NcxK bf16 row-major (= W^T).
// mode 0: Cb = bf16(acc)                       (qkv)
// mode 1: Cf = acc + bvec + Cf   (in-place)    (wo, w2)
// mode 2: Cb = bf16(gelu(acc + bvec))          (w1)
__global__ __launch_bounds__(256) void gemm_bf16_kernel(
    const short* __restrict__ A, const short* __restrict__ Bt,
    const float* __restrict__ bvec, float* __restrict__ Cf,
    short* __restrict__ Cb, int K, int Nc, int mode)
{
  __shared__ __align__(16) short As[128 * 32];
  __shared__ __align__(16) short Bs[128 * 32];
  const int bm = blockIdx.y * 128, bn = blockIdx.x * 128;
  const int t = threadIdx.x, wave = t >> 6, lane = t & 63;
  const int quad = lane >> 4, ln16 = lane & 15;
  const int wm = (wave & 1) * 64, wn = (wave >> 1) * 64;
  const int srow = lane >> 2, sseg = lane & 3;

  f32x4 acc[4][4];
#pragma unroll
  for (int i = 0; i < 4; ++i)
#pragma unroll
    for (int j = 0; j < 4; ++j) acc[i][j] = (f32x4){0.f, 0.f, 0.f, 0.f};

  for (int k0 = 0; k0 < K; k0 += 32) {
    __syncthreads();
#pragma unroll
    for (int h2 = 0; h2 < 2; ++h2) {
      int arow = wave * 16 + h2 * 64;  // wave-uniform
      const short* gpa = A + (size_t)(bm + arow + srow) * K + k0 + sseg * 8;
      __builtin_amdgcn_global_load_lds(
          (const __attribute__((address_space(1))) void*)gpa,
          (__attribute__((address_space(3))) void*)&As[arow * 32], 16, 0, 0);
      const short* gpb = Bt + (size_t)(bn + arow + srow) * K + k0 + sseg * 8;
      __builtin_amdgcn_global_load_lds(
          (const __attribute__((address_space(1))) void*)gpb,
          (__attribute__((address_space(3))) void*)&Bs[arow * 32], 16, 0, 0);
    }
    __syncthreads();
    bf16x8 af[4], bfr[4];
#pragma unroll
    for (int i = 0; i < 4; ++i)
      af[i] = *(const bf16x8*)&As[(wm + i * 16 + ln16) * 32 + quad * 8];
#pragma unroll
    for (int j = 0; j < 4; ++j)
      bfr[j] = *(const bf16x8*)&Bs[(wn + j * 16 + ln16) * 32 + quad * 8];
#pragma unroll
    for (int i = 0; i < 4; ++i)
#pragma unroll
      for (int j = 0; j < 4; ++j)
        acc[i][j] = __builtin_amdgcn_mfma_f32_16x16x32_bf16(af[i], bfr[j], acc[i][j], 0, 0, 0);
  }

  const int colbase = bn + wn + ln16;
#pragma unroll
  for (int i = 0; i < 4; ++i) {
#pragma unroll
    for (int r = 0; r < 4; ++r) {
      size_t row = (size_t)(bm + wm + i * 16 + quad * 4 + r);
      size_t off = row * Nc + colbase;
      if (mode == 0) {
#pragma unroll
        for (int j = 0; j < 4; ++j) Cb[off + j * 16] = f2bf(acc[i][j][r]);
      } else if (mode == 1) {
#pragma unroll
        for (int j = 0; j < 4; ++j) {
          float o = acc[i][j][r] + bvec[colbase + j * 16] + Cf[off + j * 16];
          Cf[off + j * 16] = o;
        }
      } else {
#pragma unroll
        for (int j = 0; j < 4; ++j)
          Cb[off + j * 16] = f2bf(gelu_f(acc[i][j][r] + bvec[colbase + j * 16]));
      }
    }
  }
}

// ---------------- MFMA flash attention (bf16 qkv input, bf16 out) ----------------
// qkv: (B*N) x 1536 bf16; q at col h*64, k at 512+h*64, v at 1024+h*64.
__global__ __launch_bounds__(256) void attn_mfma_kernel(
    const short* __restrict__ qkv, const float* __restrict__ bias,
    short* __restrict__ o)
{
  constexpr int LDR = 72;
  __shared__ __align__(16) short Qs[64 * LDR];
  __shared__ __align__(16) short Ks[64 * LDR];
  __shared__ __align__(16) short Vt[64 * LDR];
  __shared__ __align__(16) short Ps[4 * 16 * LDR];

  const int q0 = blockIdx.x * 64;
  const int hh = blockIdx.y;
  const int b  = blockIdx.z;
  const int t  = threadIdx.x;
  const int wave = t >> 6;
  const int lane = t & 63;
  const int quad = lane >> 4;
  const int ln16 = lane & 15;
  const int srow = t >> 2, sseg = t & 3;

  // ---- stage Q tile (once) ----
  {
    const short* qb = qkv + (size_t)(b * N + q0 + srow) * QKVS + hh * 64 + sseg * 16;
    *(bf16x8*)&Qs[srow * LDR + sseg * 16] = *(const bf16x8*)qb;
    *(bf16x8*)&Qs[srow * LDR + sseg * 16 + 8] = *(const bf16x8*)(qb + 8);
  }

  float m_run[4], l_run[4];
  f32x4 Oacc[4];
#pragma unroll
  for (int r = 0; r < 4; ++r) { m_run[r] = -1e30f; l_run[r] = 0.f; }
#pragma unroll
  for (int dt = 0; dt < 4; ++dt) Oacc[dt] = (f32x4){0.f, 0.f, 0.f, 0.f};

  short* Psw = Ps + wave * 16 * LDR;
  const size_t brow0 = (size_t)(b * N + q0 + wave * 16 + quad * 4) * N;

  for (int kt = 0; kt < 16; ++kt) {
    const int k0 = kt * 64;
    __syncthreads();
    // ---- stage K (row-major) and V (transposed) ----
    {
      const short* kb = qkv + (size_t)(b * N + k0 + srow) * QKVS + 512 + hh * 64 + sseg * 16;
      *(bf16x8*)&Ks[srow * LDR + sseg * 16] = *(const bf16x8*)kb;
      *(bf16x8*)&Ks[srow * LDR + sseg * 16 + 8] = *(const bf16x8*)(kb + 8);
      const short* vb = qkv + (size_t)(b * N + k0 + srow) * QKVS + 1024 + hh * 64 + sseg * 16;
      bf16x8 v0 = *(const bf16x8*)vb;
      bf16x8 v1 = *(const bf16x8*)(vb + 8);
#pragma unroll
      for (int e = 0; e < 8; ++e) {
        Vt[(sseg * 16 + e) * LDR + srow] = v0[e];
        Vt[(sseg * 16 + 8 + e) * LDR + srow] = v1[e];
      }
    }
    __syncthreads();

    // ---- S = Q K^T ----
    bf16x8 a0 = *(const bf16x8*)&Qs[(wave * 16 + ln16) * LDR + quad * 8];
    bf16x8 a1 = *(const bf16x8*)&Qs[(wave * 16 + ln16) * LDR + 32 + quad * 8];
    f32x4 sc[4];
#pragma unroll
    for (int tile = 0; tile < 4; ++tile) {
      bf16x8 b0 = *(const bf16x8*)&Ks[(tile * 16 + ln16) * LDR + quad * 8];
      bf16x8 b1 = *(const bf16x8*)&Ks[(tile * 16 + ln16) * LDR + 32 + quad * 8];
      f32x4 z = (f32x4){0.f, 0.f, 0.f, 0.f};
      z = __builtin_amdgcn_mfma_f32_16x16x32_bf16(a0, b0, z, 0, 0, 0);
      z = __builtin_amdgcn_mfma_f32_16x16x32_bf16(a1, b1, z, 0, 0, 0);
      sc[tile] = z;
    }

    // ---- scale + bias ----
    float s[4][4];
#pragma unroll
    for (int tile = 0; tile < 4; ++tile) {
      int col = k0 + tile * 16 + ln16;
#pragma unroll
      for (int r = 0; r < 4; ++r)
        s[tile][r] = sc[tile][r] * 0.125f + bias[brow0 + (size_t)r * N + col];
    }

    // ---- online softmax ----
    float p[4][4];
#pragma unroll
    for (int r = 0; r < 4; ++r) {
      float mt = fmaxf(fmaxf(s[0][r], s[1][r]), fmaxf(s[2][r], s[3][r]));
#pragma unroll
      for (int off = 1; off < 16; off <<= 1) mt = fmaxf(mt, __shfl_xor(mt, off));
      float m_new = fmaxf(m_run[r], mt);
      float al = __expf(m_run[r] - m_new);
      m_run[r] = m_new;
      float rs = 0.f;
#pragma unroll
      for (int tile = 0; tile < 4; ++tile) {
        float e = __expf(s[tile][r] - m_new);
        p[tile][r] = e;
        rs += e;
      }
#pragma unroll
      for (int off = 1; off < 16; off <<= 1) rs += __shfl_xor(rs, off);
      l_run[r] = l_run[r] * al + rs;
#pragma unroll
      for (int dt = 0; dt < 4; ++dt) Oacc[dt][r] *= al;
    }

    // ---- P (C-layout) -> LDS -> A-layout ----
#pragma unroll
    for (int tile = 0; tile < 4; ++tile)
#pragma unroll
      for (int r = 0; r < 4; ++r)
        Psw[(quad * 4 + r) * LDR + tile * 16 + ln16] = f2bf(p[tile][r]);
    __syncthreads();

    // ---- O += P V ----
    bf16x8 ap0 = *(const bf16x8*)&Psw[ln16 * LDR + quad * 8];
    bf16x8 ap1 = *(const bf16x8*)&Psw[ln16 * LDR + 32 + quad * 8];
#pragma unroll
    for (int dt = 0; dt < 4; ++dt) {
      bf16x8 bv0 = *(const bf16x8*)&Vt[(dt * 16 + ln16) * LDR + quad * 8];
      bf16x8 bv1 = *(const bf16x8*)&Vt[(dt * 16 + ln16) * LDR + 32 + quad * 8];
      Oacc[dt] = __builtin_amdgcn_mfma_f32_16x16x32_bf16(ap0, bv0, Oacc[dt], 0, 0, 0);
      Oacc[dt] = __builtin_amdgcn_mfma_f32_16x16x32_bf16(ap1, bv1, Oacc[dt], 0, 0, 0);
    }
  }

  float inv[4];
#pragma unroll
  for (int r = 0; r < 4; ++r) inv[r] = 1.0f / l_run[r];
#pragma unroll
  for (int dt = 0; dt < 4; ++dt) {
#pragma unroll
    for (int r = 0; r < 4; ++r) {
      int row = q0 + wave * 16 + quad * 4 + r;
      o[(size_t)(b * N + row) * D + hh * 64 + dt * 16 + ln16] =
          f2bf(Oacc[dt][r] * inv[r]);
    }
  }
}

}  // namespace

extern "C" void kernel_launch(void* const* d_in, const int* in_sizes, int n_in,
                              void* d_out, int out_size, void* d_ws, size_t ws_size,
                              hipStream_t stream)
{
  const float* tokens  = (const float*)d_in[0];
  const float* xy      = (const float*)d_in[1];
  const float* Wq      = (const float*)d_in[2];
  const float* Wk      = (const float*)d_in[3];
  const float* Wv      = (const float*)d_in[4];
  const float* Wo      = (const float*)d_in[5];
  const float* bo      = (const float*)d_in[6];
  const float* W1      = (const float*)d_in[7];
  const float* b1      = (const float*)d_in[8];
  const float* W2      = (const float*)d_in[9];
  const float* b2      = (const float*)d_in[10];
  const float* g1      = (const float*)d_in[11];
  const float* be1     = (const float*)d_in[12];
  const float* g2      = (const float*)d_in[13];
  const float* be2     = (const float*)d_in[14];
  const float* gf      = (const float*)d_in[15];
  const float* bf      = (const float*)d_in[16];
  const int*   alive   = (const int*)d_in[17];
  const int*   species = (const int*)d_in[18];

  char* p = (char*)d_ws;
  float* bias = (float*)p; p += (size_t)B * N * N * 4;       // 16.78 MB
  float* x    = (float*)p; p += (size_t)M * D * 4;           // 8.39 MB
  short* h    = (short*)p; p += (size_t)M * D * 2;           // 4.19 MB (LN out + attn out)
  short* qkv  = (short*)p; p += (size_t)M * DFFd * 2;        // 16.78 MB (ff aliases qkv)
  short* ff   = qkv;
  short* Wqkvt = (short*)p; p += (size_t)L * QKVS * D * 2;   // 9.44 MB
  short* Wot   = (short*)p; p += (size_t)L * D * D * 2;      // 3.15 MB
  short* W1t   = (short*)p; p += (size_t)L * DFFd * D * 2;   // 12.58 MB
  short* W2t   = (short*)p; p += (size_t)L * D * DFFd * 2;   // 12.58 MB

  hipMemcpyAsync(x, tokens, sizeof(float) * (size_t)M * D,
                 hipMemcpyDeviceToDevice, stream);
  bias_kernel<<<dim3(N / 256, N, B), 256, 0, stream>>>(xy, alive, species, bias);

  // weight prep: transpose + bf16 (batched over layers via grid.z)
  wprep_kernel<<<dim3(16, 16, L), 256, 0, stream>>>(
      Wq, Wqkvt + (size_t)0 * D * D, D, D, (size_t)D * D, (size_t)QKVS * D);
  wprep_kernel<<<dim3(16, 16, L), 256, 0, stream>>>(
      Wk, Wqkvt + (size_t)1 * D * D, D, D, (size_t)D * D, (size_t)QKVS * D);
  wprep_kernel<<<dim3(16, 16, L), 256, 0, stream>>>(
      Wv, Wqkvt + (size_t)2 * D * D, D, D, (size_t)D * D, (size_t)QKVS * D);
  wprep_kernel<<<dim3(16, 16, L), 256, 0, stream>>>(
      Wo, Wot, D, D, (size_t)D * D, (size_t)D * D);
  wprep_kernel<<<dim3(16, 64, L), 256, 0, stream>>>(
      W1, W1t, D, DFFd, (size_t)D * DFFd, (size_t)DFFd * D);
  wprep_kernel<<<dim3(64, 16, L), 256, 0, stream>>>(
      W2, W2t, DFFd, D, (size_t)DFFd * D, (size_t)D * DFFd);

  for (int l = 0; l < L; ++l) {
    ln_kernel<<<M, 64, 0, stream>>>(x, g1 + l * D, be1 + l * D, nullptr, h);
    gemm_bf16_kernel<<<dim3(QKVS / 128, M / 128), 256, 0, stream>>>(
        h, Wqkvt + (size_t)l * QKVS * D, nullptr, nullptr, qkv, D, QKVS, 0);
    attn_mfma_kernel<<<dim3(N / 64, H, B), 256, 0, stream>>>(qkv, bias, h);
    gemm_bf16_kernel<<<dim3(D / 128, M / 128), 256, 0, stream>>>(
        h, Wot + (size_t)l * D * D, bo + l * D, x, nullptr, D, D, 1);
    ln_kernel<<<M, 64, 0, stream>>>(x, g2 + l * D, be2 + l * D, nullptr, h);
    gemm_bf16_kernel<<<dim3(DFFd / 128, M / 128), 256, 0, stream>>>(
        h, W1t + (size_t)l * DFFd * D, b1 + l * DFFd, nullptr, ff, D, DFFd, 2);
    gemm_bf16_kernel<<<dim3(D / 128, M / 128), 256, 0, stream>>>(
        ff, W2t + (size_t)l * D * DFFd, b2 + l * D, x, nullptr, DFFd, D, 1);
  }
  ln_kernel<<<M, 64, 0, stream>>>(x, gf, bf, (float*)d_out, nullptr);
}

// Round 4
// 1129.671 us; speedup vs baseline: 8.6698x; 1.1078x over previous
//
#include <hip/hip_runtime.h>
#include <math.h>

namespace {

constexpr int B = 4, N = 1024, D = 512, H = 8, DHd = 64, L = 6, DFFd = 2048;
constexpr int M = B * N;           // 4096
constexpr int QKVS = 3 * D;        // 1536, qkv row stride
constexpr float NEG = -1000000000.0f;
constexpr float R2c = 100.0f;

typedef __attribute__((ext_vector_type(8))) short bf16x8;
typedef __attribute__((ext_vector_type(4))) float f32x4;

__device__ __forceinline__ short f2bf(float f) {
  union { float f; unsigned u; } c; c.f = f;
  unsigned r = (c.u + 0x7fffu + ((c.u >> 16) & 1u)) >> 16;
  return (short)r;
}

__device__ __forceinline__ float gelu_f(float x) {
  return 0.5f * x * (1.0f + erff(x * 0.70710678118654752f));
}

// ---------------- bias: (B,N,N) additive mask ----------------
__global__ __launch_bounds__(256) void bias_kernel(
    const float* __restrict__ xy, const int* __restrict__ alive,
    const int* __restrict__ species, float* __restrict__ bias)
{
  int j = blockIdx.x * 256 + threadIdx.x;
  int i = blockIdx.y;
  int b = blockIdx.z;
  float xi = xy[((size_t)b * N + i) * 2 + 0];
  float yi = xy[((size_t)b * N + i) * 2 + 1];
  float xj = xy[((size_t)b * N + j) * 2 + 0];
  float yj = xy[((size_t)b * N + j) * 2 + 1];
  float dx = xi - xj, dy = yi - yj;
  float d2 = dx * dx + dy * dy;
  float bv = 0.0f;
  if (alive[b * N + j] == 0) bv += NEG;
  if (d2 > R2c) bv += NEG;
  int si = species[b * N + i], sj = species[b * N + j];
  bool ia = si < 2, ip = si == 2, ja = sj < 2, jp = sj == 2;
  if ((ia && jp) || (ip && ja)) bv += NEG;
  bias[((size_t)b * N + i) * N + j] = bv;
}

// ---------------- weight prep: fp32 (K x Nc) -> bf16 transposed (Nc x K) ----------------
__global__ __launch_bounds__(256) void wprep_kernel(
    const float* __restrict__ src, short* __restrict__ dst,
    int K, int Nc, size_t srcLS, size_t dstLS)
{
  __shared__ float t[32][33];
  int k0 = blockIdx.x * 32, n0 = blockIdx.y * 32;
  src += (size_t)blockIdx.z * srcLS;
  dst += (size_t)blockIdx.z * dstLS;
  int r = threadIdx.x >> 5, c = threadIdx.x & 31;  // r: 0..7
#pragma unroll
  for (int i = 0; i < 4; ++i)
    t[r + i * 8][c] = src[(size_t)(k0 + r + i * 8) * Nc + n0 + c];
  __syncthreads();
#pragma unroll
  for (int i = 0; i < 4; ++i)
    dst[(size_t)(n0 + r + i * 8) * K + k0 + c] = f2bf(t[c][r + i * 8]);
}

// ---------------- LayerNorm: one wave per row of 512; bf16 or fp32 out ----------------
__global__ __launch_bounds__(64) void ln_kernel(
    const float* __restrict__ x, const float* __restrict__ g,
    const float* __restrict__ be, float* __restrict__ outf,
    short* __restrict__ outb)
{
  int row = blockIdx.x;
  int tid = threadIdx.x;
  const float* xr = x + (size_t)row * D;
  float v[8];
  float sum = 0.f;
#pragma unroll
  for (int i = 0; i < 8; ++i) { v[i] = xr[tid + i * 64]; sum += v[i]; }
#pragma unroll
  for (int off = 32; off > 0; off >>= 1) sum += __shfl_down(sum, off);
  sum = __shfl(sum, 0);
  float mean = sum * (1.0f / D);
  float vs = 0.f;
#pragma unroll
  for (int i = 0; i < 8; ++i) { float d = v[i] - mean; vs += d * d; }
#pragma unroll
  for (int off = 32; off > 0; off >>= 1) vs += __shfl_down(vs, off);
  vs = __shfl(vs, 0);
  float rstd = rsqrtf(vs * (1.0f / D) + 1e-5f);
#pragma unroll
  for (int i = 0; i < 8; ++i) {
    int c = tid + i * 64;
    float o = (v[i] - mean) * rstd * g[c] + be[c];
    if (outb) outb[(size_t)row * D + c] = f2bf(o);
    else      outf[(size_t)row * D + c] = o;
  }
}

// ---------------- bf16 MFMA GEMM, double-buffered (ping-pong) ----------------
// A: Mx K bf16 row-major. Bt: Nc x K bf16 row-major (= W^T).
// BN = N-tile (64 or 128), NJ = BN/32 per-wave j-tiles.
// mode 0: Cb = bf16(acc);  mode 1: Cf = acc + bvec + Cf (in-place);
// mode 2: Cb = bf16(gelu(acc + bvec)).
template <int BN, int NJ>
__global__ __launch_bounds__(256) void gemm_db_kernel(
    const short* __restrict__ A, const short* __restrict__ Bt,
    const float* __restrict__ bvec, float* __restrict__ Cf,
    short* __restrict__ Cb, int K, int Nc, int mode)
{
  __shared__ __align__(16) short As[2][128 * 32];
  __shared__ __align__(16) short Bs[2][BN * 32];
  const int bm = blockIdx.y * 128, bn = blockIdx.x * BN;
  const int t = threadIdx.x, wave = t >> 6, lane = t & 63;
  const int quad = lane >> 4, ln16 = lane & 15;
  const int wm = (wave & 1) * 64, wn = (wave >> 1) * (16 * NJ);
  const int srow = lane >> 2, sseg = lane & 3;
  constexpr int PEND = 2 + BN / 64;  // loads issued per tile (per thread)

  const short* Abase = A + (size_t)(bm + wave * 16 + srow) * K + sseg * 8;
  const short* Bbase = Bt + (size_t)(bn + wave * 16 + srow) * K + sseg * 8;
  const int nk = K >> 5;

  auto issue = [&](int p, int k0) {
#pragma unroll
    for (int h2 = 0; h2 < 2; ++h2) {
      __builtin_amdgcn_global_load_lds(
          (const __attribute__((address_space(1))) void*)(Abase + (size_t)h2 * 64 * K + k0),
          (__attribute__((address_space(3))) void*)&As[p][(wave * 16 + h2 * 64) * 32],
          16, 0, 0);
    }
#pragma unroll
    for (int h2 = 0; h2 < BN / 64; ++h2) {
      __builtin_amdgcn_global_load_lds(
          (const __attribute__((address_space(1))) void*)(Bbase + (size_t)h2 * 64 * K + k0),
          (__attribute__((address_space(3))) void*)&Bs[p][(wave * 16 + h2 * 64) * 32],
          16, 0, 0);
    }
  };

  f32x4 acc[4][NJ];
#pragma unroll
  for (int i = 0; i < 4; ++i)
#pragma unroll
    for (int j = 0; j < NJ; ++j) acc[i][j] = (f32x4){0.f, 0.f, 0.f, 0.f};

  issue(0, 0);
  for (int kt = 0; kt < nk; ++kt) {
    const int p = kt & 1;
    if (kt + 1 < nk) {
      issue(p ^ 1, (kt + 1) << 5);
      asm volatile("s_waitcnt vmcnt(%0)" :: "i"(PEND) : "memory");
    } else {
      asm volatile("s_waitcnt vmcnt(0)" ::: "memory");
    }
    asm volatile("s_barrier" ::: "memory");  // buf p ready for all waves
    bf16x8 af[4], bfr[NJ];
#pragma unroll
    for (int i = 0; i < 4; ++i)
      af[i] = *(const bf16x8*)&As[p][(wm + i * 16 + ln16) * 32 + quad * 8];
#pragma unroll
    for (int j = 0; j < NJ; ++j)
      bfr[j] = *(const bf16x8*)&Bs[p][(wn + j * 16 + ln16) * 32 + quad * 8];
#pragma unroll
    for (int i = 0; i < 4; ++i)
#pragma unroll
      for (int j = 0; j < NJ; ++j)
        acc[i][j] = __builtin_amdgcn_mfma_f32_16x16x32_bf16(af[i], bfr[j], acc[i][j], 0, 0, 0);
    asm volatile("s_barrier" ::: "memory");  // all reads of buf p done before overwrite
  }

  const int colbase = bn + wn + ln16;
#pragma unroll
  for (int i = 0; i < 4; ++i) {
#pragma unroll
    for (int r = 0; r < 4; ++r) {
      size_t row = (size_t)(bm + wm + i * 16 + quad * 4 + r);
      size_t off = row * Nc + colbase;
      if (mode == 0) {
#pragma unroll
        for (int j = 0; j < NJ; ++j) Cb[off + j * 16] = f2bf(acc[i][j][r]);
      } else if (mode == 1) {
#pragma unroll
        for (int j = 0; j < NJ; ++j) {
          float o = acc[i][j][r] + bvec[colbase + j * 16] + Cf[off + j * 16];
          Cf[off + j * 16] = o;
        }
      } else {
#pragma unroll
        for (int j = 0; j < NJ; ++j)
          Cb[off + j * 16] = f2bf(gelu_f(acc[i][j][r] + bvec[colbase + j * 16]));
      }
    }
  }
}

// ---------------- MFMA flash attention (bf16 qkv input, bf16 out) ----------------
// qkv: (B*N) x 1536 bf16; q at col h*64, k at 512+h*64, v at 1024+h*64.
__global__ __launch_bounds__(256) void attn_mfma_kernel(
    const short* __restrict__ qkv, const float* __restrict__ bias,
    short* __restrict__ o)
{
  constexpr int LDR = 72;
  __shared__ __align__(16) short Qs[64 * LDR];
  __shared__ __align__(16) short Ks[64 * LDR];
  __shared__ __align__(16) short Vt[64 * LDR];
  __shared__ __align__(16) short Ps[4 * 16 * LDR];

  const int q0 = blockIdx.x * 64;
  const int hh = blockIdx.y;
  const int b  = blockIdx.z;
  const int t  = threadIdx.x;
  const int wave = t >> 6;
  const int lane = t & 63;
  const int quad = lane >> 4;
  const int ln16 = lane & 15;
  const int srow = t >> 2, sseg = t & 3;

  // ---- stage Q tile (once) ----
  {
    const short* qb = qkv + (size_t)(b * N + q0 + srow) * QKVS + hh * 64 + sseg * 16;
    *(bf16x8*)&Qs[srow * LDR + sseg * 16] = *(const bf16x8*)qb;
    *(bf16x8*)&Qs[srow * LDR + sseg * 16 + 8] = *(const bf16x8*)(qb + 8);
  }

  float m_run[4], l_run[4];
  f32x4 Oacc[4];
#pragma unroll
  for (int r = 0; r < 4; ++r) { m_run[r] = -1e30f; l_run[r] = 0.f; }
#pragma unroll
  for (int dt = 0; dt < 4; ++dt) Oacc[dt] = (f32x4){0.f, 0.f, 0.f, 0.f};

  short* Psw = Ps + wave * 16 * LDR;
  const size_t brow0 = (size_t)(b * N + q0 + wave * 16 + quad * 4) * N;

  for (int kt = 0; kt < 16; ++kt) {
    const int k0 = kt * 64;
    __syncthreads();
    // ---- stage K (row-major) and V (transposed) ----
    {
      const short* kb = qkv + (size_t)(b * N + k0 + srow) * QKVS + 512 + hh * 64 + sseg * 16;
      *(bf16x8*)&Ks[srow * LDR + sseg * 16] = *(const bf16x8*)kb;
      *(bf16x8*)&Ks[srow * LDR + sseg * 16 + 8] = *(const bf16x8*)(kb + 8);
      const short* vb = qkv + (size_t)(b * N + k0 + srow) * QKVS + 1024 + hh * 64 + sseg * 16;
      bf16x8 v0 = *(const bf16x8*)vb;
      bf16x8 v1 = *(const bf16x8*)(vb + 8);
#pragma unroll
      for (int e = 0; e < 8; ++e) {
        Vt[(sseg * 16 + e) * LDR + srow] = v0[e];
        Vt[(sseg * 16 + 8 + e) * LDR + srow] = v1[e];
      }
    }
    __syncthreads();

    // ---- S = Q K^T ----
    bf16x8 a0 = *(const bf16x8*)&Qs[(wave * 16 + ln16) * LDR + quad * 8];
    bf16x8 a1 = *(const bf16x8*)&Qs[(wave * 16 + ln16) * LDR + 32 + quad * 8];
    f32x4 sc[4];
#pragma unroll
    for (int tile = 0; tile < 4; ++tile) {
      bf16x8 b0 = *(const bf16x8*)&Ks[(tile * 16 + ln16) * LDR + quad * 8];
      bf16x8 b1 = *(const bf16x8*)&Ks[(tile * 16 + ln16) * LDR + 32 + quad * 8];
      f32x4 z = (f32x4){0.f, 0.f, 0.f, 0.f};
      z = __builtin_amdgcn_mfma_f32_16x16x32_bf16(a0, b0, z, 0, 0, 0);
      z = __builtin_amdgcn_mfma_f32_16x16x32_bf16(a1, b1, z, 0, 0, 0);
      sc[tile] = z;
    }

    // ---- scale + bias ----
    float s[4][4];
#pragma unroll
    for (int tile = 0; tile < 4; ++tile) {
      int col = k0 + tile * 16 + ln16;
#pragma unroll
      for (int r = 0; r < 4; ++r)
        s[tile][r] = sc[tile][r] * 0.125f + bias[brow0 + (size_t)r * N + col];
    }

    // ---- online softmax ----
    float p[4][4];
#pragma unroll
    for (int r = 0; r < 4; ++r) {
      float mt = fmaxf(fmaxf(s[0][r], s[1][r]), fmaxf(s[2][r], s[3][r]));
#pragma unroll
      for (int off = 1; off < 16; off <<= 1) mt = fmaxf(mt, __shfl_xor(mt, off));
      float m_new = fmaxf(m_run[r], mt);
      float al = __expf(m_run[r] - m_new);
      m_run[r] = m_new;
      float rs = 0.f;
#pragma unroll
      for (int tile = 0; tile < 4; ++tile) {
        float e = __expf(s[tile][r] - m_new);
        p[tile][r] = e;
        rs += e;
      }
#pragma unroll
      for (int off = 1; off < 16; off <<= 1) rs += __shfl_xor(rs, off);
      l_run[r] = l_run[r] * al + rs;
#pragma unroll
      for (int dt = 0; dt < 4; ++dt) Oacc[dt][r] *= al;
    }

    // ---- P (C-layout) -> LDS -> A-layout ----
#pragma unroll
    for (int tile = 0; tile < 4; ++tile)
#pragma unroll
      for (int r = 0; r < 4; ++r)
        Psw[(quad * 4 + r) * LDR + tile * 16 + ln16] = f2bf(p[tile][r]);
    __syncthreads();

    // ---- O += P V ----
    bf16x8 ap0 = *(const bf16x8*)&Psw[ln16 * LDR + quad * 8];
    bf16x8 ap1 = *(const bf16x8*)&Psw[ln16 * LDR + 32 + quad * 8];
#pragma unroll
    for (int dt = 0; dt < 4; ++dt) {
      bf16x8 bv0 = *(const bf16x8*)&Vt[(dt * 16 + ln16) * LDR + quad * 8];
      bf16x8 bv1 = *(const bf16x8*)&Vt[(dt * 16 + ln16) * LDR + 32 + quad * 8];
      Oacc[dt] = __builtin_amdgcn_mfma_f32_16x16x32_bf16(ap0, bv0, Oacc[dt], 0, 0, 0);
      Oacc[dt] = __builtin_amdgcn_mfma_f32_16x16x32_bf16(ap1, bv1, Oacc[dt], 0, 0, 0);
    }
  }

  float inv[4];
#pragma unroll
  for (int r = 0; r < 4; ++r) inv[r] = 1.0f / l_run[r];
#pragma unroll
  for (int dt = 0; dt < 4; ++dt) {
#pragma unroll
    for (int r = 0; r < 4; ++r) {
      int row = q0 + wave * 16 + quad * 4 + r;
      o[(size_t)(b * N + row) * D + hh * 64 + dt * 16 + ln16] =
          f2bf(Oacc[dt][r] * inv[r]);
    }
  }
}

}  // namespace

extern "C" void kernel_launch(void* const* d_in, const int* in_sizes, int n_in,
                              void* d_out, int out_size, void* d_ws, size_t ws_size,
                              hipStream_t stream)
{
  const float* tokens  = (const float*)d_in[0];
  const float* xy      = (const float*)d_in[1];
  const float* Wq      = (const float*)d_in[2];
  const float* Wk      = (const float*)d_in[3];
  const float* Wv      = (const float*)d_in[4];
  const float* Wo      = (const float*)d_in[5];
  const float* bo      = (const float*)d_in[6];
  const float* W1      = (const float*)d_in[7];
  const float* b1      = (const float*)d_in[8];
  const float* W2      = (const float*)d_in[9];
  const float* b2      = (const float*)d_in[10];
  const float* g1      = (const float*)d_in[11];
  const float* be1     = (const float*)d_in[12];
  const float* g2      = (const float*)d_in[13];
  const float* be2     = (const float*)d_in[14];
  const float* gf      = (const float*)d_in[15];
  const float* bf      = (const float*)d_in[16];
  const int*   alive   = (const int*)d_in[17];
  const int*   species = (const int*)d_in[18];

  char* p = (char*)d_ws;
  float* bias = (float*)p; p += (size_t)B * N * N * 4;       // 16.78 MB
  float* x    = (float*)p; p += (size_t)M * D * 4;           // 8.39 MB
  short* h    = (short*)p; p += (size_t)M * D * 2;           // 4.19 MB
  short* qkv  = (short*)p; p += (size_t)M * DFFd * 2;        // 16.78 MB (ff aliases qkv)
  short* ff   = qkv;
  short* Wqkvt = (short*)p; p += (size_t)L * QKVS * D * 2;   // 9.44 MB
  short* Wot   = (short*)p; p += (size_t)L * D * D * 2;      // 3.15 MB
  short* W1t   = (short*)p; p += (size_t)L * DFFd * D * 2;   // 12.58 MB
  short* W2t   = (short*)p; p += (size_t)L * D * DFFd * 2;   // 12.58 MB

  hipMemcpyAsync(x, tokens, sizeof(float) * (size_t)M * D,
                 hipMemcpyDeviceToDevice, stream);
  bias_kernel<<<dim3(N / 256, N, B), 256, 0, stream>>>(xy, alive, species, bias);

  wprep_kernel<<<dim3(16, 16, L), 256, 0, stream>>>(
      Wq, Wqkvt + (size_t)0 * D * D, D, D, (size_t)D * D, (size_t)QKVS * D);
  wprep_kernel<<<dim3(16, 16, L), 256, 0, stream>>>(
      Wk, Wqkvt + (size_t)1 * D * D, D, D, (size_t)D * D, (size_t)QKVS * D);
  wprep_kernel<<<dim3(16, 16, L), 256, 0, stream>>>(
      Wv, Wqkvt + (size_t)2 * D * D, D, D, (size_t)D * D, (size_t)QKVS * D);
  wprep_kernel<<<dim3(16, 16, L), 256, 0, stream>>>(
      Wo, Wot, D, D, (size_t)D * D, (size_t)D * D);
  wprep_kernel<<<dim3(16, 64, L), 256, 0, stream>>>(
      W1, W1t, D, DFFd, (size_t)D * DFFd, (size_t)DFFd * D);
  wprep_kernel<<<dim3(64, 16, L), 256, 0, stream>>>(
      W2, W2t, DFFd, D, (size_t)DFFd * D, (size_t)D * DFFd);

  for (int l = 0; l < L; ++l) {
    ln_kernel<<<M, 64, 0, stream>>>(x, g1 + l * D, be1 + l * D, nullptr, h);
    gemm_db_kernel<128, 4><<<dim3(QKVS / 128, M / 128), 256, 0, stream>>>(
        h, Wqkvt + (size_t)l * QKVS * D, nullptr, nullptr, qkv, D, QKVS, 0);
    attn_mfma_kernel<<<dim3(N / 64, H, B), 256, 0, stream>>>(qkv, bias, h);
    gemm_db_kernel<64, 2><<<dim3(D / 64, M / 128), 256, 0, stream>>>(
        h, Wot + (size_t)l * D * D, bo + l * D, x, nullptr, D, D, 1);
    ln_kernel<<<M, 64, 0, stream>>>(x, g2 + l * D, be2 + l * D, nullptr, h);
    gemm_db_kernel<128, 4><<<dim3(DFFd / 128, M / 128), 256, 0, stream>>>(
        h, W1t + (size_t)l * DFFd * D, b1 + l * DFFd, nullptr, ff, D, DFFd, 2);
    gemm_db_kernel<64, 2><<<dim3(D / 64, M / 128), 256, 0, stream>>>(
        ff, W2t + (size_t)l * D * DFFd, b2 + l * D, x, nullptr, DFFd, D, 1);
  }
  ln_kernel<<<M, 64, 0, stream>>>(x, gf, bf, (float*)d_out, nullptr);
}

// Round 5
// 1037.656 us; speedup vs baseline: 9.4386x; 1.0887x over previous
//
#include <hip/hip_runtime.h>
#include <math.h>

namespace {

constexpr int B = 4, N = 1024, D = 512, H = 8, DHd = 64, L = 6, DFFd = 2048;
constexpr int M = B * N;           // 4096
constexpr int QKVS = 3 * D;        // 1536, qkv row stride
constexpr float NEG = -1000000000.0f;
constexpr float R2c = 100.0f;

typedef __attribute__((ext_vector_type(8))) short bf16x8;
typedef __attribute__((ext_vector_type(4))) float f32x4;

__device__ __forceinline__ short f2bf(float f) {
  union { float f; unsigned u; } c; c.f = f;
  unsigned r = (c.u + 0x7fffu + ((c.u >> 16) & 1u)) >> 16;
  return (short)r;
}

__device__ __forceinline__ float gelu_f(float x) {
  return 0.5f * x * (1.0f + erff(x * 0.70710678118654752f));
}

// ---------------- bias: (B,N,N) additive mask ----------------
__global__ __launch_bounds__(256) void bias_kernel(
    const float* __restrict__ xy, const int* __restrict__ alive,
    const int* __restrict__ species, float* __restrict__ bias)
{
  int j = blockIdx.x * 256 + threadIdx.x;
  int i = blockIdx.y;
  int b = blockIdx.z;
  float xi = xy[((size_t)b * N + i) * 2 + 0];
  float yi = xy[((size_t)b * N + i) * 2 + 1];
  float xj = xy[((size_t)b * N + j) * 2 + 0];
  float yj = xy[((size_t)b * N + j) * 2 + 1];
  float dx = xi - xj, dy = yi - yj;
  float d2 = dx * dx + dy * dy;
  float bv = 0.0f;
  if (alive[b * N + j] == 0) bv += NEG;
  if (d2 > R2c) bv += NEG;
  int si = species[b * N + i], sj = species[b * N + j];
  bool ia = si < 2, ip = si == 2, ja = sj < 2, jp = sj == 2;
  if ((ia && jp) || (ip && ja)) bv += NEG;
  bias[((size_t)b * N + i) * N + j] = bv;
}

// ---------------- weight prep: fp32 (K x Nc) -> bf16 transposed (Nc x K) ----------------
__global__ __launch_bounds__(256) void wprep_kernel(
    const float* __restrict__ src, short* __restrict__ dst,
    int K, int Nc, size_t srcLS, size_t dstLS)
{
  __shared__ float t[32][33];
  int k0 = blockIdx.x * 32, n0 = blockIdx.y * 32;
  src += (size_t)blockIdx.z * srcLS;
  dst += (size_t)blockIdx.z * dstLS;
  int r = threadIdx.x >> 5, c = threadIdx.x & 31;  // r: 0..7
#pragma unroll
  for (int i = 0; i < 4; ++i)
    t[r + i * 8][c] = src[(size_t)(k0 + r + i * 8) * Nc + n0 + c];
  __syncthreads();
#pragma unroll
  for (int i = 0; i < 4; ++i)
    dst[(size_t)(n0 + r + i * 8) * K + k0 + c] = f2bf(t[c][r + i * 8]);
}

// ---------------- LayerNorm: one wave per row of 512; bf16 or fp32 out ----------------
__global__ __launch_bounds__(64) void ln_kernel(
    const float* __restrict__ x, const float* __restrict__ g,
    const float* __restrict__ be, float* __restrict__ outf,
    short* __restrict__ outb)
{
  int row = blockIdx.x;
  int tid = threadIdx.x;
  const float* xr = x + (size_t)row * D;
  float v[8];
  float sum = 0.f;
#pragma unroll
  for (int i = 0; i < 8; ++i) { v[i] = xr[tid + i * 64]; sum += v[i]; }
#pragma unroll
  for (int off = 32; off > 0; off >>= 1) sum += __shfl_down(sum, off);
  sum = __shfl(sum, 0);
  float mean = sum * (1.0f / D);
  float vs = 0.f;
#pragma unroll
  for (int i = 0; i < 8; ++i) { float d = v[i] - mean; vs += d * d; }
#pragma unroll
  for (int off = 32; off > 0; off >>= 1) vs += __shfl_down(vs, off);
  vs = __shfl(vs, 0);
  float rstd = rsqrtf(vs * (1.0f / D) + 1e-5f);
#pragma unroll
  for (int i = 0; i < 8; ++i) {
    int c = tid + i * 64;
    float o = (v[i] - mean) * rstd * g[c] + be[c];
    if (outb) outb[(size_t)row * D + c] = f2bf(o);
    else      outf[(size_t)row * D + c] = o;
  }
}

// ---------------- bf16 MFMA GEMM, double-buffered (ping-pong) ----------------
template <int BN, int NJ>
__global__ __launch_bounds__(256) void gemm_db_kernel(
    const short* __restrict__ A, const short* __restrict__ Bt,
    const float* __restrict__ bvec, float* __restrict__ Cf,
    short* __restrict__ Cb, int K, int Nc, int mode)
{
  __shared__ __align__(16) short As[2][128 * 32];
  __shared__ __align__(16) short Bs[2][BN * 32];
  const int bm = blockIdx.y * 128, bn = blockIdx.x * BN;
  const int t = threadIdx.x, wave = t >> 6, lane = t & 63;
  const int quad = lane >> 4, ln16 = lane & 15;
  const int wm = (wave & 1) * 64, wn = (wave >> 1) * (16 * NJ);
  const int srow = lane >> 2, sseg = lane & 3;
  constexpr int PEND = 2 + BN / 64;

  const short* Abase = A + (size_t)(bm + wave * 16 + srow) * K + sseg * 8;
  const short* Bbase = Bt + (size_t)(bn + wave * 16 + srow) * K + sseg * 8;
  const int nk = K >> 5;

  auto issue = [&](int p, int k0) {
#pragma unroll
    for (int h2 = 0; h2 < 2; ++h2) {
      __builtin_amdgcn_global_load_lds(
          (const __attribute__((address_space(1))) void*)(Abase + (size_t)h2 * 64 * K + k0),
          (__attribute__((address_space(3))) void*)&As[p][(wave * 16 + h2 * 64) * 32],
          16, 0, 0);
    }
#pragma unroll
    for (int h2 = 0; h2 < BN / 64; ++h2) {
      __builtin_amdgcn_global_load_lds(
          (const __attribute__((address_space(1))) void*)(Bbase + (size_t)h2 * 64 * K + k0),
          (__attribute__((address_space(3))) void*)&Bs[p][(wave * 16 + h2 * 64) * 32],
          16, 0, 0);
    }
  };

  f32x4 acc[4][NJ];
#pragma unroll
  for (int i = 0; i < 4; ++i)
#pragma unroll
    for (int j = 0; j < NJ; ++j) acc[i][j] = (f32x4){0.f, 0.f, 0.f, 0.f};

  issue(0, 0);
  for (int kt = 0; kt < nk; ++kt) {
    const int p = kt & 1;
    if (kt + 1 < nk) {
      issue(p ^ 1, (kt + 1) << 5);
      asm volatile("s_waitcnt vmcnt(%0)" :: "i"(PEND) : "memory");
    } else {
      asm volatile("s_waitcnt vmcnt(0)" ::: "memory");
    }
    asm volatile("s_barrier" ::: "memory");
    bf16x8 af[4], bfr[NJ];
#pragma unroll
    for (int i = 0; i < 4; ++i)
      af[i] = *(const bf16x8*)&As[p][(wm + i * 16 + ln16) * 32 + quad * 8];
#pragma unroll
    for (int j = 0; j < NJ; ++j)
      bfr[j] = *(const bf16x8*)&Bs[p][(wn + j * 16 + ln16) * 32 + quad * 8];
#pragma unroll
    for (int i = 0; i < 4; ++i)
#pragma unroll
      for (int j = 0; j < NJ; ++j)
        acc[i][j] = __builtin_amdgcn_mfma_f32_16x16x32_bf16(af[i], bfr[j], acc[i][j], 0, 0, 0);
    asm volatile("s_barrier" ::: "memory");
  }

  const int colbase = bn + wn + ln16;
#pragma unroll
  for (int i = 0; i < 4; ++i) {
#pragma unroll
    for (int r = 0; r < 4; ++r) {
      size_t row = (size_t)(bm + wm + i * 16 + quad * 4 + r);
      size_t off = row * Nc + colbase;
      if (mode == 0) {
#pragma unroll
        for (int j = 0; j < NJ; ++j) Cb[off + j * 16] = f2bf(acc[i][j][r]);
      } else if (mode == 1) {
#pragma unroll
        for (int j = 0; j < NJ; ++j) {
          float o = acc[i][j][r] + bvec[colbase + j * 16] + Cf[off + j * 16];
          Cf[off + j * 16] = o;
        }
      } else {
#pragma unroll
        for (int j = 0; j < NJ; ++j)
          Cb[off + j * 16] = f2bf(gelu_f(acc[i][j][r] + bvec[colbase + j * 16]));
      }
    }
  }
}

// ---------------- MFMA flash attention v2: S^T orientation, 1 barrier/ktile ----------------
// qkv: (B*N) x 1536 bf16; q at col h*64, k at 512+h*64, v at 1024+h*64. Out: bf16.
// Block = 64 queries x 1 head; wave w owns queries [q0+16w, q0+16w+16).
// S^T = K Q^T: lane (quad,ln16) holds keys {ks*16+quad*4+r} for query q=ln16.
__global__ __launch_bounds__(256) void attn_mfma_kernel(
    const short* __restrict__ qkv, const float* __restrict__ bias,
    short* __restrict__ o)
{
  constexpr int LDR = 72;
  __shared__ __align__(16) short Qs[64 * LDR];
  __shared__ __align__(16) short Ks[2][64 * LDR];
  __shared__ __align__(16) short Vt[2][64 * LDR];
  __shared__ __align__(16) short Ps[4 * 16 * LDR];

  const int q0 = blockIdx.x * 64;
  const int hh = blockIdx.y;
  const int b  = blockIdx.z;
  const int t  = threadIdx.x;
  const int wave = t >> 6;
  const int lane = t & 63;
  const int quad = lane >> 4;
  const int ln16 = lane & 15;
  const int srow = t >> 2, sseg = t & 3;

  // ---- stage Q (padded rows, 2x b128 per thread) ----
  {
    const short* qb = qkv + (size_t)(b * N + q0 + srow) * QKVS + hh * 64 + sseg * 16;
    *(bf16x8*)&Qs[srow * LDR + sseg * 16] = *(const bf16x8*)qb;
    *(bf16x8*)&Qs[srow * LDR + sseg * 16 + 8] = *(const bf16x8*)(qb + 8);
  }
  __syncthreads();

  // hoisted loop-invariant Q B-fragments (this wave's 16-query band)
  const int qrow = wave * 16 + ln16;
  const bf16x8 qf0 = *(const bf16x8*)&Qs[qrow * LDR + quad * 8];
  const bf16x8 qf1 = *(const bf16x8*)&Qs[qrow * LDR + 32 + quad * 8];

  float m_run = -1e30f, l_run = 0.f;   // per lane: query q = q0+wave*16+ln16
  f32x4 Oacc[4];
#pragma unroll
  for (int dt = 0; dt < 4; ++dt) Oacc[dt] = (f32x4){0.f, 0.f, 0.f, 0.f};

  short* Psw = Ps + wave * 16 * LDR;
  const float* brow = bias + (size_t)(b * N + q0 + wave * 16 + ln16) * N;
  const short* kb0 = qkv + (size_t)b * N * QKVS + 512 + hh * 64 + sseg * 16;
  const short* vb0 = qkv + (size_t)b * N * QKVS + 1024 + hh * 64 + sseg * 16;

  // prefetch tile 0 into registers
  bf16x8 k0r = *(const bf16x8*)(kb0 + (size_t)srow * QKVS);
  bf16x8 k1r = *(const bf16x8*)(kb0 + (size_t)srow * QKVS + 8);
  bf16x8 v0r = *(const bf16x8*)(vb0 + (size_t)srow * QKVS);
  bf16x8 v1r = *(const bf16x8*)(vb0 + (size_t)srow * QKVS + 8);
  float4 b4[4];
#pragma unroll
  for (int ks = 0; ks < 4; ++ks)
    b4[ks] = *(const float4*)&brow[ks * 16 + quad * 4];

  for (int kt = 0; kt < 16; ++kt) {
    const int p = kt & 1;
    // (A) stage current K/V tile from regs into LDS buffer p
    *(bf16x8*)&Ks[p][srow * LDR + sseg * 16] = k0r;
    *(bf16x8*)&Ks[p][srow * LDR + sseg * 16 + 8] = k1r;
#pragma unroll
    for (int e = 0; e < 8; ++e) {
      Vt[p][(sseg * 16 + e) * LDR + srow] = v0r[e];
      Vt[p][(sseg * 16 + 8 + e) * LDR + srow] = v1r[e];
    }
    // (B) issue global prefetch for tile kt+1 (stays in flight across barrier)
    const int k0n = (kt + 1 < 16) ? (kt + 1) * 64 : 0;
    bf16x8 nk0 = *(const bf16x8*)(kb0 + (size_t)(k0n + srow) * QKVS);
    bf16x8 nk1 = *(const bf16x8*)(kb0 + (size_t)(k0n + srow) * QKVS + 8);
    bf16x8 nv0 = *(const bf16x8*)(vb0 + (size_t)(k0n + srow) * QKVS);
    bf16x8 nv1 = *(const bf16x8*)(vb0 + (size_t)(k0n + srow) * QKVS + 8);
    float4 bcur[4] = {b4[0], b4[1], b4[2], b4[3]};
#pragma unroll
    for (int ks = 0; ks < 4; ++ks)
      b4[ks] = *(const float4*)&brow[k0n + ks * 16 + quad * 4];
    // (C) single barrier: LDS writes visible; global loads NOT drained
    asm volatile("s_waitcnt lgkmcnt(0)\n\ts_barrier" ::: "memory");

    // (D1) S^T = K Q^T  (4 key-subtiles x 2 d-halves)
    float sv[4][4];
#pragma unroll
    for (int ks = 0; ks < 4; ++ks) {
      bf16x8 a0 = *(const bf16x8*)&Ks[p][(ks * 16 + ln16) * LDR + quad * 8];
      bf16x8 a1 = *(const bf16x8*)&Ks[p][(ks * 16 + ln16) * LDR + 32 + quad * 8];
      f32x4 z = (f32x4){0.f, 0.f, 0.f, 0.f};
      z = __builtin_amdgcn_mfma_f32_16x16x32_bf16(a0, qf0, z, 0, 0, 0);
      z = __builtin_amdgcn_mfma_f32_16x16x32_bf16(a1, qf1, z, 0, 0, 0);
#pragma unroll
      for (int r = 0; r < 4; ++r)
        sv[ks][r] = z[r] * 0.125f + (&bcur[ks].x)[r];
    }

    // (D2) online softmax: row = query (per lane), 16 key-values in registers
    float mt = sv[0][0];
#pragma unroll
    for (int ks = 0; ks < 4; ++ks)
#pragma unroll
      for (int r = 0; r < 4; ++r) mt = fmaxf(mt, sv[ks][r]);
    mt = fmaxf(mt, __shfl_xor(mt, 16));
    mt = fmaxf(mt, __shfl_xor(mt, 32));
    const float m_new = fmaxf(m_run, mt);
    const float alpha = __expf(m_run - m_new);
    m_run = m_new;
    float rs = 0.f;
    float pv[4][4];
#pragma unroll
    for (int ks = 0; ks < 4; ++ks)
#pragma unroll
      for (int r = 0; r < 4; ++r) {
        float e = __expf(sv[ks][r] - m_new);
        pv[ks][r] = e;
        rs += e;
      }
    rs += __shfl_xor(rs, 16);
    rs += __shfl_xor(rs, 32);
    l_run = l_run * alpha + rs;
    // alpha lives at lane q=ln16; O rows are q=quad*4+r -> gather
    float af[4];
#pragma unroll
    for (int r = 0; r < 4; ++r) af[r] = __shfl(alpha, quad * 4 + r);
#pragma unroll
    for (int dt = 0; dt < 4; ++dt)
#pragma unroll
      for (int r = 0; r < 4; ++r) Oacc[dt][r] *= af[r];

    // (D3) P -> Ps[q][key] (4x ds_write_b64, r-contiguous keys)
#pragma unroll
    for (int ks = 0; ks < 4; ++ks) {
      short4 pk = {f2bf(pv[ks][0]), f2bf(pv[ks][1]), f2bf(pv[ks][2]), f2bf(pv[ks][3])};
      *(short4*)&Psw[ln16 * LDR + ks * 16 + quad * 4] = pk;
    }

    // (D4) O += P V   (A=Ps wave-private; B=Vt[p] shared, barrier-ordered)
    bf16x8 ap0 = *(const bf16x8*)&Psw[ln16 * LDR + quad * 8];
    bf16x8 ap1 = *(const bf16x8*)&Psw[ln16 * LDR + 32 + quad * 8];
#pragma unroll
    for (int dt = 0; dt < 4; ++dt) {
      bf16x8 bv0 = *(const bf16x8*)&Vt[p][(dt * 16 + ln16) * LDR + quad * 8];
      bf16x8 bv1 = *(const bf16x8*)&Vt[p][(dt * 16 + ln16) * LDR + 32 + quad * 8];
      Oacc[dt] = __builtin_amdgcn_mfma_f32_16x16x32_bf16(ap0, bv0, Oacc[dt], 0, 0, 0);
      Oacc[dt] = __builtin_amdgcn_mfma_f32_16x16x32_bf16(ap1, bv1, Oacc[dt], 0, 0, 0);
    }

    k0r = nk0; k1r = nk1; v0r = nv0; v1r = nv1;
  }

  // epilogue: gather 1/l for rows quad*4+r, write bf16
  const float linv = 1.0f / l_run;
  float iv[4];
#pragma unroll
  for (int r = 0; r < 4; ++r) iv[r] = __shfl(linv, quad * 4 + r);
#pragma unroll
  for (int dt = 0; dt < 4; ++dt) {
#pragma unroll
    for (int r = 0; r < 4; ++r) {
      int row = q0 + wave * 16 + quad * 4 + r;
      o[(size_t)(b * N + row) * D + hh * 64 + dt * 16 + ln16] =
          f2bf(Oacc[dt][r] * iv[r]);
    }
  }
}

}  // namespace

extern "C" void kernel_launch(void* const* d_in, const int* in_sizes, int n_in,
                              void* d_out, int out_size, void* d_ws, size_t ws_size,
                              hipStream_t stream)
{
  const float* tokens  = (const float*)d_in[0];
  const float* xy      = (const float*)d_in[1];
  const float* Wq      = (const float*)d_in[2];
  const float* Wk      = (const float*)d_in[3];
  const float* Wv      = (const float*)d_in[4];
  const float* Wo      = (const float*)d_in[5];
  const float* bo      = (const float*)d_in[6];
  const float* W1      = (const float*)d_in[7];
  const float* b1      = (const float*)d_in[8];
  const float* W2      = (const float*)d_in[9];
  const float* b2      = (const float*)d_in[10];
  const float* g1      = (const float*)d_in[11];
  const float* be1     = (const float*)d_in[12];
  const float* g2      = (const float*)d_in[13];
  const float* be2     = (const float*)d_in[14];
  const float* gf      = (const float*)d_in[15];
  const float* bf      = (const float*)d_in[16];
  const int*   alive   = (const int*)d_in[17];
  const int*   species = (const int*)d_in[18];

  char* p = (char*)d_ws;
  float* bias = (float*)p; p += (size_t)B * N * N * 4;       // 16.78 MB
  float* x    = (float*)p; p += (size_t)M * D * 4;           // 8.39 MB
  short* h    = (short*)p; p += (size_t)M * D * 2;           // 4.19 MB
  short* qkv  = (short*)p; p += (size_t)M * DFFd * 2;        // 16.78 MB (ff aliases qkv)
  short* ff   = qkv;
  short* Wqkvt = (short*)p; p += (size_t)L * QKVS * D * 2;   // 9.44 MB
  short* Wot   = (short*)p; p += (size_t)L * D * D * 2;      // 3.15 MB
  short* W1t   = (short*)p; p += (size_t)L * DFFd * D * 2;   // 12.58 MB
  short* W2t   = (short*)p; p += (size_t)L * D * DFFd * 2;   // 12.58 MB

  hipMemcpyAsync(x, tokens, sizeof(float) * (size_t)M * D,
                 hipMemcpyDeviceToDevice, stream);
  bias_kernel<<<dim3(N / 256, N, B), 256, 0, stream>>>(xy, alive, species, bias);

  wprep_kernel<<<dim3(16, 16, L), 256, 0, stream>>>(
      Wq, Wqkvt + (size_t)0 * D * D, D, D, (size_t)D * D, (size_t)QKVS * D);
  wprep_kernel<<<dim3(16, 16, L), 256, 0, stream>>>(
      Wk, Wqkvt + (size_t)1 * D * D, D, D, (size_t)D * D, (size_t)QKVS * D);
  wprep_kernel<<<dim3(16, 16, L), 256, 0, stream>>>(
      Wv, Wqkvt + (size_t)2 * D * D, D, D, (size_t)D * D, (size_t)QKVS * D);
  wprep_kernel<<<dim3(16, 16, L), 256, 0, stream>>>(
      Wo, Wot, D, D, (size_t)D * D, (size_t)D * D);
  wprep_kernel<<<dim3(16, 64, L), 256, 0, stream>>>(
      W1, W1t, D, DFFd, (size_t)D * DFFd, (size_t)DFFd * D);
  wprep_kernel<<<dim3(64, 16, L), 256, 0, stream>>>(
      W2, W2t, DFFd, D, (size_t)DFFd * D, (size_t)D * DFFd);

  for (int l = 0; l < L; ++l) {
    ln_kernel<<<M, 64, 0, stream>>>(x, g1 + l * D, be1 + l * D, nullptr, h);
    gemm_db_kernel<128, 4><<<dim3(QKVS / 128, M / 128), 256, 0, stream>>>(
        h, Wqkvt + (size_t)l * QKVS * D, nullptr, nullptr, qkv, D, QKVS, 0);
    attn_mfma_kernel<<<dim3(N / 64, H, B), 256, 0, stream>>>(qkv, bias, h);
    gemm_db_kernel<64, 2><<<dim3(D / 64, M / 128), 256, 0, stream>>>(
        h, Wot + (size_t)l * D * D, bo + l * D, x, nullptr, D, D, 1);
    ln_kernel<<<M, 64, 0, stream>>>(x, g2 + l * D, be2 + l * D, nullptr, h);
    gemm_db_kernel<128, 4><<<dim3(DFFd / 128, M / 128), 256, 0, stream>>>(
        h, W1t + (size_t)l * DFFd * D, b1 + l * DFFd, nullptr, ff, D, DFFd, 2);
    gemm_db_kernel<64, 2><<<dim3(D / 64, M / 128), 256, 0, stream>>>(
        ff, W2t + (size_t)l * D * DFFd, b2 + l * D, x, nullptr, DFFd, D, 1);
  }
  ln_kernel<<<M, 64, 0, stream>>>(x, gf, bf, (float*)d_out, nullptr);
}

// Round 6
// 994.447 us; speedup vs baseline: 9.8487x; 1.0435x over previous
//
#include <hip/hip_runtime.h>
#include <math.h>

namespace {

constexpr int B = 4, N = 1024, D = 512, H = 8, DHd = 64, L = 6, DFFd = 2048;
constexpr int M = B * N;           // 4096
constexpr int QKVS = 3 * D;        // 1536, qkv row stride
constexpr float NEG = -1000000000.0f;
constexpr float R2c = 100.0f;

typedef __attribute__((ext_vector_type(8))) short bf16x8;
typedef __attribute__((ext_vector_type(4))) float f32x4;
typedef __attribute__((ext_vector_type(16))) float f32x16;

__device__ __forceinline__ short f2bf(float f) {
  union { float f; unsigned u; } c; c.f = f;
  unsigned r = (c.u + 0x7fffu + ((c.u >> 16) & 1u)) >> 16;
  return (short)r;
}

__device__ __forceinline__ float gelu_f(float x) {
  return 0.5f * x * (1.0f + erff(x * 0.70710678118654752f));
}

// ---------------- bias: (B,N,N) additive mask ----------------
__global__ __launch_bounds__(256) void bias_kernel(
    const float* __restrict__ xy, const int* __restrict__ alive,
    const int* __restrict__ species, float* __restrict__ bias)
{
  int j = blockIdx.x * 256 + threadIdx.x;
  int i = blockIdx.y;
  int b = blockIdx.z;
  float xi = xy[((size_t)b * N + i) * 2 + 0];
  float yi = xy[((size_t)b * N + i) * 2 + 1];
  float xj = xy[((size_t)b * N + j) * 2 + 0];
  float yj = xy[((size_t)b * N + j) * 2 + 1];
  float dx = xi - xj, dy = yi - yj;
  float d2 = dx * dx + dy * dy;
  float bv = 0.0f;
  if (alive[b * N + j] == 0) bv += NEG;
  if (d2 > R2c) bv += NEG;
  int si = species[b * N + i], sj = species[b * N + j];
  bool ia = si < 2, ip = si == 2, ja = sj < 2, jp = sj == 2;
  if ((ia && jp) || (ip && ja)) bv += NEG;
  bias[((size_t)b * N + i) * N + j] = bv;
}

// ---------------- weight prep: fp32 (K x Nc) -> bf16 transposed (Nc x K) ----------------
__global__ __launch_bounds__(256) void wprep_kernel(
    const float* __restrict__ src, short* __restrict__ dst,
    int K, int Nc, size_t srcLS, size_t dstLS)
{
  __shared__ float t[32][33];
  int k0 = blockIdx.x * 32, n0 = blockIdx.y * 32;
  src += (size_t)blockIdx.z * srcLS;
  dst += (size_t)blockIdx.z * dstLS;
  int r = threadIdx.x >> 5, c = threadIdx.x & 31;  // r: 0..7
#pragma unroll
  for (int i = 0; i < 4; ++i)
    t[r + i * 8][c] = src[(size_t)(k0 + r + i * 8) * Nc + n0 + c];
  __syncthreads();
#pragma unroll
  for (int i = 0; i < 4; ++i)
    dst[(size_t)(n0 + r + i * 8) * K + k0 + c] = f2bf(t[c][r + i * 8]);
}

// ---------------- LayerNorm: one wave per row of 512; bf16 or fp32 out ----------------
__global__ __launch_bounds__(64) void ln_kernel(
    const float* __restrict__ x, const float* __restrict__ g,
    const float* __restrict__ be, float* __restrict__ outf,
    short* __restrict__ outb)
{
  int row = blockIdx.x;
  int tid = threadIdx.x;
  const float* xr = x + (size_t)row * D;
  float v[8];
  float sum = 0.f;
#pragma unroll
  for (int i = 0; i < 8; ++i) { v[i] = xr[tid + i * 64]; sum += v[i]; }
#pragma unroll
  for (int off = 32; off > 0; off >>= 1) sum += __shfl_down(sum, off);
  sum = __shfl(sum, 0);
  float mean = sum * (1.0f / D);
  float vs = 0.f;
#pragma unroll
  for (int i = 0; i < 8; ++i) { float d = v[i] - mean; vs += d * d; }
#pragma unroll
  for (int off = 32; off > 0; off >>= 1) vs += __shfl_down(vs, off);
  vs = __shfl(vs, 0);
  float rstd = rsqrtf(vs * (1.0f / D) + 1e-5f);
#pragma unroll
  for (int i = 0; i < 8; ++i) {
    int c = tid + i * 64;
    float o = (v[i] - mean) * rstd * g[c] + be[c];
    if (outb) outb[(size_t)row * D + c] = f2bf(o);
    else      outf[(size_t)row * D + c] = o;
  }
}

// ---------------- split-K bf16 MFMA GEMM: barrier-free K-loop ----------------
// Block = 64x64 C-tile, 4 waves; wave w accumulates over K-slice [w*K/4,(w+1)*K/4)
// into a full 64x64 partial (2x2 tiles of mfma_f32_32x32x16_bf16), staging its
// own chunks into wave-private LDS via global_load_lds (no intra-loop barriers).
// One __syncthreads, then padded-LDS 4-way reduction + fused epilogue.
// mode 0: Cb = bf16(acc); mode 1: Cf = acc+bvec+Cf (in-place); mode 2: Cb=bf16(gelu(acc+bvec)).
__global__ __launch_bounds__(256, 2) void gemm_sk_kernel(
    const short* __restrict__ A, const short* __restrict__ Bt,
    const float* __restrict__ bvec, float* __restrict__ Cf,
    short* __restrict__ Cb, int K, int Nc, int mode)
{
  // per-wave slot: 17408 B. staging: A buf p at +p*8192, B buf p at +p*8192+4096.
  // reduction: float[64][68] per wave (17408 B), overlaps staging after main loop.
  __shared__ __align__(16) char smem[4 * 17408];
  const int bm = blockIdx.y * 64, bn = blockIdx.x * 64;
  const int t = threadIdx.x, wave = t >> 6, lane = t & 63;
  const int half = lane >> 5;          // 0..1 (k-half for 32x32x16 frags)
  const int l32 = lane & 31;           // m or n within tile
  const int srow4 = lane >> 2, sseg4 = lane & 3;  // staging coords

  char* slot = smem + wave * 17408;
  const int kw0 = wave * (K >> 2);
  const int nch = K >> 7;              // chunks of 32 per wave

  const short* Ab = A + (size_t)(bm + srow4) * K + kw0 + sseg4 * 8;
  const short* Bb = Bt + (size_t)(bn + srow4) * K + kw0 + sseg4 * 8;

  auto issue = [&](int p, int kc) {
    char* ab = slot + p * 8192;
    char* bb = slot + p * 8192 + 4096;
#pragma unroll
    for (int i = 0; i < 4; ++i) {
      __builtin_amdgcn_global_load_lds(
          (const __attribute__((address_space(1))) void*)(Ab + (size_t)i * 16 * K + kc),
          (__attribute__((address_space(3))) void*)(ab + i * 1024), 16, 0, 0);
    }
#pragma unroll
    for (int i = 0; i < 4; ++i) {
      __builtin_amdgcn_global_load_lds(
          (const __attribute__((address_space(1))) void*)(Bb + (size_t)i * 16 * K + kc),
          (__attribute__((address_space(3))) void*)(bb + i * 1024), 16, 0, 0);
    }
  };

  f32x16 acc[2][2];
#pragma unroll
  for (int i = 0; i < 2; ++i)
#pragma unroll
    for (int j = 0; j < 2; ++j)
#pragma unroll
      for (int r = 0; r < 16; ++r) acc[i][j][r] = 0.f;

  issue(0, 0);
  for (int c = 0; c < nch; ++c) {
    const int p = c & 1;
    if (c + 1 < nch) {
      issue(p ^ 1, (c + 1) * 32);
      asm volatile("s_waitcnt vmcnt(%0)" :: "i"(8) : "memory");
    } else {
      asm volatile("s_waitcnt vmcnt(0)" ::: "memory");
    }
    const short* As = (const short*)(slot + p * 8192);
    const short* Bs = (const short*)(slot + p * 8192 + 4096);
#pragma unroll
    for (int ks = 0; ks < 2; ++ks) {
      bf16x8 a0 = *(const bf16x8*)&As[(l32) * 32 + ks * 16 + half * 8];
      bf16x8 a1 = *(const bf16x8*)&As[(32 + l32) * 32 + ks * 16 + half * 8];
      bf16x8 b0 = *(const bf16x8*)&Bs[(l32) * 32 + ks * 16 + half * 8];
      bf16x8 b1 = *(const bf16x8*)&Bs[(32 + l32) * 32 + ks * 16 + half * 8];
      acc[0][0] = __builtin_amdgcn_mfma_f32_32x32x16_bf16(a0, b0, acc[0][0], 0, 0, 0);
      acc[0][1] = __builtin_amdgcn_mfma_f32_32x32x16_bf16(a0, b1, acc[0][1], 0, 0, 0);
      acc[1][0] = __builtin_amdgcn_mfma_f32_32x32x16_bf16(a1, b0, acc[1][0], 0, 0, 0);
      acc[1][1] = __builtin_amdgcn_mfma_f32_32x32x16_bf16(a1, b1, acc[1][1], 0, 0, 0);
    }
  }

  // ---- write per-wave partial into padded LDS region [64][68] f32 ----
  float* red = (float*)slot;
#pragma unroll
  for (int ti = 0; ti < 2; ++ti)
#pragma unroll
    for (int tj = 0; tj < 2; ++tj)
#pragma unroll
      for (int r = 0; r < 16; ++r) {
        int row = ti * 32 + (r & 3) + 8 * (r >> 2) + 4 * half;
        red[row * 68 + tj * 32 + l32] = acc[ti][tj][r];
      }
  __syncthreads();

  // ---- 4-way reduce + fused epilogue ----
  const int row = t >> 2, cs = (t & 3) * 16;
  const size_t orow = (size_t)(bm + row) * Nc + bn + cs;
#pragma unroll
  for (int u = 0; u < 4; ++u) {
    float4 s0 = *(const float4*)((const float*)(smem + 0 * 17408) + row * 68 + cs + u * 4);
    float4 s1 = *(const float4*)((const float*)(smem + 1 * 17408) + row * 68 + cs + u * 4);
    float4 s2 = *(const float4*)((const float*)(smem + 2 * 17408) + row * 68 + cs + u * 4);
    float4 s3 = *(const float4*)((const float*)(smem + 3 * 17408) + row * 68 + cs + u * 4);
    float o0 = s0.x + s1.x + s2.x + s3.x;
    float o1 = s0.y + s1.y + s2.y + s3.y;
    float o2 = s0.z + s1.z + s2.z + s3.z;
    float o3 = s0.w + s1.w + s2.w + s3.w;
    const int col = bn + cs + u * 4;
    if (mode == 0) {
      short4 w = {f2bf(o0), f2bf(o1), f2bf(o2), f2bf(o3)};
      *(short4*)&Cb[orow + u * 4] = w;
    } else if (mode == 1) {
      float4 bv = *(const float4*)&bvec[col];
      float4 rv = *(const float4*)&Cf[orow + u * 4];
      float4 w = {o0 + bv.x + rv.x, o1 + bv.y + rv.y, o2 + bv.z + rv.z, o3 + bv.w + rv.w};
      *(float4*)&Cf[orow + u * 4] = w;
    } else {
      float4 bv = *(const float4*)&bvec[col];
      short4 w = {f2bf(gelu_f(o0 + bv.x)), f2bf(gelu_f(o1 + bv.y)),
                  f2bf(gelu_f(o2 + bv.z)), f2bf(gelu_f(o3 + bv.w))};
      *(short4*)&Cb[orow + u * 4] = w;
    }
  }
}

// ---------------- MFMA flash attention v2: S^T orientation, 1 barrier/ktile ----------------
__global__ __launch_bounds__(256) void attn_mfma_kernel(
    const short* __restrict__ qkv, const float* __restrict__ bias,
    short* __restrict__ o)
{
  constexpr int LDR = 72;
  __shared__ __align__(16) short Qs[64 * LDR];
  __shared__ __align__(16) short Ks[2][64 * LDR];
  __shared__ __align__(16) short Vt[2][64 * LDR];
  __shared__ __align__(16) short Ps[4 * 16 * LDR];

  const int q0 = blockIdx.x * 64;
  const int hh = blockIdx.y;
  const int b  = blockIdx.z;
  const int t  = threadIdx.x;
  const int wave = t >> 6;
  const int lane = t & 63;
  const int quad = lane >> 4;
  const int ln16 = lane & 15;
  const int srow = t >> 2, sseg = t & 3;

  {
    const short* qb = qkv + (size_t)(b * N + q0 + srow) * QKVS + hh * 64 + sseg * 16;
    *(bf16x8*)&Qs[srow * LDR + sseg * 16] = *(const bf16x8*)qb;
    *(bf16x8*)&Qs[srow * LDR + sseg * 16 + 8] = *(const bf16x8*)(qb + 8);
  }
  __syncthreads();

  const int qrow = wave * 16 + ln16;
  const bf16x8 qf0 = *(const bf16x8*)&Qs[qrow * LDR + quad * 8];
  const bf16x8 qf1 = *(const bf16x8*)&Qs[qrow * LDR + 32 + quad * 8];

  float m_run = -1e30f, l_run = 0.f;
  f32x4 Oacc[4];
#pragma unroll
  for (int dt = 0; dt < 4; ++dt) Oacc[dt] = (f32x4){0.f, 0.f, 0.f, 0.f};

  short* Psw = Ps + wave * 16 * LDR;
  const float* brow = bias + (size_t)(b * N + q0 + wave * 16 + ln16) * N;
  const short* kb0 = qkv + (size_t)b * N * QKVS + 512 + hh * 64 + sseg * 16;
  const short* vb0 = qkv + (size_t)b * N * QKVS + 1024 + hh * 64 + sseg * 16;

  bf16x8 k0r = *(const bf16x8*)(kb0 + (size_t)srow * QKVS);
  bf16x8 k1r = *(const bf16x8*)(kb0 + (size_t)srow * QKVS + 8);
  bf16x8 v0r = *(const bf16x8*)(vb0 + (size_t)srow * QKVS);
  bf16x8 v1r = *(const bf16x8*)(vb0 + (size_t)srow * QKVS + 8);
  float4 b4[4];
#pragma unroll
  for (int ks = 0; ks < 4; ++ks)
    b4[ks] = *(const float4*)&brow[ks * 16 + quad * 4];

  for (int kt = 0; kt < 16; ++kt) {
    const int p = kt & 1;
    *(bf16x8*)&Ks[p][srow * LDR + sseg * 16] = k0r;
    *(bf16x8*)&Ks[p][srow * LDR + sseg * 16 + 8] = k1r;
#pragma unroll
    for (int e = 0; e < 8; ++e) {
      Vt[p][(sseg * 16 + e) * LDR + srow] = v0r[e];
      Vt[p][(sseg * 16 + 8 + e) * LDR + srow] = v1r[e];
    }
    const int k0n = (kt + 1 < 16) ? (kt + 1) * 64 : 0;
    bf16x8 nk0 = *(const bf16x8*)(kb0 + (size_t)(k0n + srow) * QKVS);
    bf16x8 nk1 = *(const bf16x8*)(kb0 + (size_t)(k0n + srow) * QKVS + 8);
    bf16x8 nv0 = *(const bf16x8*)(vb0 + (size_t)(k0n + srow) * QKVS);
    bf16x8 nv1 = *(const bf16x8*)(vb0 + (size_t)(k0n + srow) * QKVS + 8);
    float4 bcur[4] = {b4[0], b4[1], b4[2], b4[3]};
#pragma unroll
    for (int ks = 0; ks < 4; ++ks)
      b4[ks] = *(const float4*)&brow[k0n + ks * 16 + quad * 4];
    asm volatile("s_waitcnt lgkmcnt(0)\n\ts_barrier" ::: "memory");

    float sv[4][4];
#pragma unroll
    for (int ks = 0; ks < 4; ++ks) {
      bf16x8 a0 = *(const bf16x8*)&Ks[p][(ks * 16 + ln16) * LDR + quad * 8];
      bf16x8 a1 = *(const bf16x8*)&Ks[p][(ks * 16 + ln16) * LDR + 32 + quad * 8];
      f32x4 z = (f32x4){0.f, 0.f, 0.f, 0.f};
      z = __builtin_amdgcn_mfma_f32_16x16x32_bf16(a0, qf0, z, 0, 0, 0);
      z = __builtin_amdgcn_mfma_f32_16x16x32_bf16(a1, qf1, z, 0, 0, 0);
#pragma unroll
      for (int r = 0; r < 4; ++r)
        sv[ks][r] = z[r] * 0.125f + (&bcur[ks].x)[r];
    }

    float mt = sv[0][0];
#pragma unroll
    for (int ks = 0; ks < 4; ++ks)
#pragma unroll
      for (int r = 0; r < 4; ++r) mt = fmaxf(mt, sv[ks][r]);
    mt = fmaxf(mt, __shfl_xor(mt, 16));
    mt = fmaxf(mt, __shfl_xor(mt, 32));
    const float m_new = fmaxf(m_run, mt);
    const float alpha = __expf(m_run - m_new);
    m_run = m_new;
    float rs = 0.f;
    float pv[4][4];
#pragma unroll
    for (int ks = 0; ks < 4; ++ks)
#pragma unroll
      for (int r = 0; r < 4; ++r) {
        float e = __expf(sv[ks][r] - m_new);
        pv[ks][r] = e;
        rs += e;
      }
    rs += __shfl_xor(rs, 16);
    rs += __shfl_xor(rs, 32);
    l_run = l_run * alpha + rs;
    float af[4];
#pragma unroll
    for (int r = 0; r < 4; ++r) af[r] = __shfl(alpha, quad * 4 + r);
#pragma unroll
    for (int dt = 0; dt < 4; ++dt)
#pragma unroll
      for (int r = 0; r < 4; ++r) Oacc[dt][r] *= af[r];

#pragma unroll
    for (int ks = 0; ks < 4; ++ks) {
      short4 pk = {f2bf(pv[ks][0]), f2bf(pv[ks][1]), f2bf(pv[ks][2]), f2bf(pv[ks][3])};
      *(short4*)&Psw[ln16 * LDR + ks * 16 + quad * 4] = pk;
    }

    bf16x8 ap0 = *(const bf16x8*)&Psw[ln16 * LDR + quad * 8];
    bf16x8 ap1 = *(const bf16x8*)&Psw[ln16 * LDR + 32 + quad * 8];
#pragma unroll
    for (int dt = 0; dt < 4; ++dt) {
      bf16x8 bv0 = *(const bf16x8*)&Vt[p][(dt * 16 + ln16) * LDR + quad * 8];
      bf16x8 bv1 = *(const bf16x8*)&Vt[p][(dt * 16 + ln16) * LDR + 32 + quad * 8];
      Oacc[dt] = __builtin_amdgcn_mfma_f32_16x16x32_bf16(ap0, bv0, Oacc[dt], 0, 0, 0);
      Oacc[dt] = __builtin_amdgcn_mfma_f32_16x16x32_bf16(ap1, bv1, Oacc[dt], 0, 0, 0);
    }

    k0r = nk0; k1r = nk1; v0r = nv0; v1r = nv1;
  }

  const float linv = 1.0f / l_run;
  float iv[4];
#pragma unroll
  for (int r = 0; r < 4; ++r) iv[r] = __shfl(linv, quad * 4 + r);
#pragma unroll
  for (int dt = 0; dt < 4; ++dt) {
#pragma unroll
    for (int r = 0; r < 4; ++r) {
      int row = q0 + wave * 16 + quad * 4 + r;
      o[(size_t)(b * N + row) * D + hh * 64 + dt * 16 + ln16] =
          f2bf(Oacc[dt][r] * iv[r]);
    }
  }
}

}  // namespace

extern "C" void kernel_launch(void* const* d_in, const int* in_sizes, int n_in,
                              void* d_out, int out_size, void* d_ws, size_t ws_size,
                              hipStream_t stream)
{
  const float* tokens  = (const float*)d_in[0];
  const float* xy      = (const float*)d_in[1];
  const float* Wq      = (const float*)d_in[2];
  const float* Wk      = (const float*)d_in[3];
  const float* Wv      = (const float*)d_in[4];
  const float* Wo      = (const float*)d_in[5];
  const float* bo      = (const float*)d_in[6];
  const float* W1      = (const float*)d_in[7];
  const float* b1      = (const float*)d_in[8];
  const float* W2      = (const float*)d_in[9];
  const float* b2      = (const float*)d_in[10];
  const float* g1      = (const float*)d_in[11];
  const float* be1     = (const float*)d_in[12];
  const float* g2      = (const float*)d_in[13];
  const float* be2     = (const float*)d_in[14];
  const float* gf      = (const float*)d_in[15];
  const float* bf      = (const float*)d_in[16];
  const int*   alive   = (const int*)d_in[17];
  const int*   species = (const int*)d_in[18];

  char* p = (char*)d_ws;
  float* bias = (float*)p; p += (size_t)B * N * N * 4;       // 16.78 MB
  float* x    = (float*)p; p += (size_t)M * D * 4;           // 8.39 MB
  short* h    = (short*)p; p += (size_t)M * D * 2;           // 4.19 MB
  short* qkv  = (short*)p; p += (size_t)M * DFFd * 2;        // 16.78 MB (ff aliases qkv)
  short* ff   = qkv;
  short* Wqkvt = (short*)p; p += (size_t)L * QKVS * D * 2;   // 9.44 MB
  short* Wot   = (short*)p; p += (size_t)L * D * D * 2;      // 3.15 MB
  short* W1t   = (short*)p; p += (size_t)L * DFFd * D * 2;   // 12.58 MB
  short* W2t   = (short*)p; p += (size_t)L * D * DFFd * 2;   // 12.58 MB

  hipMemcpyAsync(x, tokens, sizeof(float) * (size_t)M * D,
                 hipMemcpyDeviceToDevice, stream);
  bias_kernel<<<dim3(N / 256, N, B), 256, 0, stream>>>(xy, alive, species, bias);

  wprep_kernel<<<dim3(16, 16, L), 256, 0, stream>>>(
      Wq, Wqkvt + (size_t)0 * D * D, D, D, (size_t)D * D, (size_t)QKVS * D);
  wprep_kernel<<<dim3(16, 16, L), 256, 0, stream>>>(
      Wk, Wqkvt + (size_t)1 * D * D, D, D, (size_t)D * D, (size_t)QKVS * D);
  wprep_kernel<<<dim3(16, 16, L), 256, 0, stream>>>(
      Wv, Wqkvt + (size_t)2 * D * D, D, D, (size_t)D * D, (size_t)QKVS * D);
  wprep_kernel<<<dim3(16, 16, L), 256, 0, stream>>>(
      Wo, Wot, D, D, (size_t)D * D, (size_t)D * D);
  wprep_kernel<<<dim3(16, 64, L), 256, 0, stream>>>(
      W1, W1t, D, DFFd, (size_t)D * DFFd, (size_t)DFFd * D);
  wprep_kernel<<<dim3(64, 16, L), 256, 0, stream>>>(
      W2, W2t, DFFd, D, (size_t)DFFd * D, (size_t)D * DFFd);

  for (int l = 0; l < L; ++l) {
    ln_kernel<<<M, 64, 0, stream>>>(x, g1 + l * D, be1 + l * D, nullptr, h);
    gemm_sk_kernel<<<dim3(QKVS / 64, M / 64), 256, 0, stream>>>(
        h, Wqkvt + (size_t)l * QKVS * D, nullptr, nullptr, qkv, D, QKVS, 0);
    attn_mfma_kernel<<<dim3(N / 64, H, B), 256, 0, stream>>>(qkv, bias, h);
    gemm_sk_kernel<<<dim3(D / 64, M / 64), 256, 0, stream>>>(
        h, Wot + (size_t)l * D * D, bo + l * D, x, nullptr, D, D, 1);
    ln_kernel<<<M, 64, 0, stream>>>(x, g2 + l * D, be2 + l * D, nullptr, h);
    gemm_sk_kernel<<<dim3(DFFd / 64, M / 64), 256, 0, stream>>>(
        h, W1t + (size_t)l * DFFd * D, b1 + l * DFFd, nullptr, ff, D, DFFd, 2);
    gemm_sk_kernel<<<dim3(D / 64, M / 64), 256, 0, stream>>>(
        ff, W2t + (size_t)l * D * DFFd, b2 + l * D, x, nullptr, DFFd, D, 1);
  }
  ln_kernel<<<M, 64, 0, stream>>>(x, gf, bf, (float*)d_out, nullptr);
}